// Round 3
// baseline (2273.376 us; speedup 1.0000x reference)
//
#include <hip/hip_runtime.h>
#include <hip/hip_bf16.h>

// B=2, S=2048, W=32, D=1024, H=16, hd=64
// Pipeline (full path):
//   bf16-cast: Wq,Wk,Wv,Wo,q (small only)
//   K/V GEMM: gemm_big = 256x256 tile, BK=64, 8-phase schedule with FUSED
//             fp32->bf16 A-cast. A: reg-staged (4x global_load_dwordx4
//             issued 5 phases ahead -> v_cvt_pk_bf16_f32 -> swizzled
//             ds_write_b128, CVTs ONLY in ph3 (buf0) / ph7 (buf1) after all
//             reads of that region complete). B: global_load_lds.
//             ALL vmcnt drains at phase END followed by s_barrier
//             (drain->barrier->read invariant; round-2 violated this).
//             Steady drains ph2/4/6/8 = 12/10/12/10 (worst-case-permutation
//             safe: required op is always oldest at its drain).
//   Q/O GEMM: gemm_lds (128x128)
//   attn: per (b,s') head-softmax gather-attention -> A (4096x1024 bf16)
//   out  = A@Wo^T+bo (fp32)

#define DEVI __device__ __forceinline__

typedef __attribute__((ext_vector_type(8))) short bf16x8;
typedef __attribute__((ext_vector_type(4))) float f32x4;
typedef const __attribute__((address_space(1))) void* gvp;
typedef __attribute__((address_space(3))) void* lvp;

DEVI ushort f2bf(float f) {
  uint u = __float_as_uint(f);
  u = u + 0x7fffu + ((u >> 16) & 1u);
  return (ushort)(u >> 16);
}
DEVI float bf2f(ushort u) { return __uint_as_float(((uint)u) << 16); }

// ---------------- elementwise fp32 -> bf16 cast (RNE), 8 elems/thread ----
__global__ __launch_bounds__(256) void cast_kernel(const float* __restrict__ in,
                                                   ushort* __restrict__ out,
                                                   long n) {
  long i = ((long)blockIdx.x * 256 + threadIdx.x) * 8;
  const long stride = (long)gridDim.x * 256 * 8;
  for (; i < n; i += stride) {
    float4 a = *reinterpret_cast<const float4*>(in + i);
    float4 b = *reinterpret_cast<const float4*>(in + i + 4);
    ushort o[8];
    o[0] = f2bf(a.x); o[1] = f2bf(a.y); o[2] = f2bf(a.z); o[3] = f2bf(a.w);
    o[4] = f2bf(b.x); o[5] = f2bf(b.y); o[6] = f2bf(b.z); o[7] = f2bf(b.w);
    *reinterpret_cast<int4*>(out + i) = *reinterpret_cast<const int4*>(o);
  }
}

// ---------------- fused-cast 8-phase GEMM: C = A(fp32) @ W(bf16)^T + bias --
// Tile 256(M)x256(N), K=1024, BK=64, 16 K-tiles, 8 iters x 2 tiles.
// LDS (bf16): buf0: A0@0 A1@16K B0@32K B1@48K; buf1 = +64K. Each half =
// 128 rows x 64 cols (row 128B = 8 chunks of 16B); stored chunk p of row r
// holds source chunk p^(r&7); read swz ((kk*4+q)^(lm&7))*16.
// Schedule (j = 2*it; steady M=0):
//  ph1: LDA aF, LDB bF (buf0)      STG B0(j+1)->buf1.B0          mfma<0,0>
//  ph2: AISS sc=A0(j+3)            STG B1(j+1)->buf1.B1  LDA aG  mfma<4,0>
//       end: vmcnt(12)+bar   [buf0.B1(j) resident for ph3]
//  ph3: CVT sa->buf0.A0(j+2) CVT sb->buf0.A1(j+2) AISS sd=A1(j+3) LDB bG
//                                                                mfma<0,2>
//  ph4:                                                          mfma<4,2>
//       end: vmcnt(10)+bar   [buf1.B0(j+1) resident for ph5]
//  ph5: LDA aF, LDB bF (buf1)      STG B0(j+2)->buf0.B0          mfma<0,0>
//  ph6: AISS sa=A0(j+4)            STG B1(j+2)->buf0.B1  LDA aG  mfma<4,0>
//       end: vmcnt(12)+bar   [buf1.B1(j+1) resident for ph7]
//  ph7: CVT sc->buf1.A0(j+3) CVT sd->buf1.A1(j+3) AISS sb=A1(j+4) LDB bG
//                                                                mfma<0,2>
//  ph8:                                                          mfma<4,2>
//       end: vmcnt(10)+bar   [buf0.B0(j+2) resident for next ph1]
// Region safety: buf.A last read in ph2/ph6 (aG) -> written in ph3/ph7;
// CVT visibility via writer's lgkmcnt(0) (PH_SYNC) + barriers.
// Tails: it6 (M=1) skips AISS sa/sb (drains 12/10/8/2);
//        it7 (M=2) skips all AISS/CVT + ph5/ph6 STGs (drains 4/2/0/-).
template <int FI0, int FJ0>
DEVI void mfma16(f32x4 (&acc)[8][4], const bf16x8 (&A)[4][2],
                 const bf16x8 (&B)[2][2]) {
  __builtin_amdgcn_s_setprio(1);
#pragma unroll
  for (int i = 0; i < 4; ++i)
#pragma unroll
    for (int j = 0; j < 2; ++j)
#pragma unroll
      for (int kk = 0; kk < 2; ++kk)
        acc[FI0 + i][FJ0 + j] = __builtin_amdgcn_mfma_f32_16x16x32_bf16(
            A[i][kk], B[j][kk], acc[FI0 + i][FJ0 + j], 0, 0, 0);
  __builtin_amdgcn_s_setprio(0);
}

__global__ __launch_bounds__(512, 2) void gemm_big(const float* __restrict__ Ag,
                                                   const ushort* __restrict__ Wg,
                                                   const float* __restrict__ bias,
                                                   ushort* __restrict__ Cg) {
  constexpr int K = 1024;
  __shared__ char lds[131072];
  const int tid = threadIdx.x;
  const int lane = tid & 63;
  const int wave = tid >> 6;
  const int wm = wave >> 2;
  const int wn = wave & 3;
  const int d = blockIdx.x;
  const int bn = (d >> 3) & 3;
  const size_t bm = (size_t)(d & 7) * (gridDim.x >> 5) + (d >> 5);

  const ushort* bB = Wg + (size_t)bn * 256 * K;

  // staging geometry: chunk f=tid -> row r0=tid>>3, pos tid&7; source chunk
  // c0=(tid&7)^(r0&7) (same for r0+64k). A is fp32: chunk = 8 floats.
  const int r0 = tid >> 3;
  const int c0 = (tid & 7) ^ (r0 & 7);
  const float* pR0 = Ag + bm * 256 * K + (size_t)r0 * K + c0 * 8;
  const float* pR1 = pR0 + 64 * K;
  const ushort* bS0 = bB + (size_t)r0 * K + c0 * 8;
  const ushort* bS1 = bB + (size_t)(r0 + 64) * K + c0 * 8;
  const ushort* bS2 = bB + (size_t)(r0 + 128) * K + c0 * 8;
  const ushort* bS3 = bB + (size_t)(r0 + 192) * K + c0 * 8;

  // fragment-read offsets
  const int lm = lane & 15;
  const int q = lane >> 4;
  const int rowB = lm * 128;
  const int swz0 = (q ^ (lm & 7)) * 16;
  const int swz1 = ((4 + q) ^ (lm & 7)) * 16;
  const char* ldsc = (const char*)lds;
  const char* p0A = ldsc + wm * 16384 + rowB;
  const char* p0B = ldsc + 32768 + (wn >> 1) * 16384 + (wn & 1) * 8192 + rowB;
  const char* p1A = p0A + 65536;
  const char* p1B = p0B + 65536;

  f32x4 acc[8][4] = {};
  bf16x8 aF[4][2], aG[4][2], bF[2][2], bG[2][2];
  float4 sa[4], sb[4], sc[4], sd[4];

#define SB0 __builtin_amdgcn_sched_barrier(0)
#define STG(p0, p1, ktE, ldsOff)                                                 \
  {                                                                              \
    __builtin_amdgcn_global_load_lds((gvp)((p0) + (ktE)),                        \
                                     (lvp)(lds + (ldsOff) + tid * 16), 16, 0, 0);\
    __builtin_amdgcn_global_load_lds((gvp)((p1) + (ktE)),                        \
                                     (lvp)(lds + (ldsOff) + 8192 + tid * 16),    \
                                     16, 0, 0);                                  \
  }
#define AISS(set, off)                                                \
  {                                                                   \
    set[0] = *reinterpret_cast<const float4*>(pR0 + (off));           \
    set[1] = *reinterpret_cast<const float4*>(pR0 + (off) + 4);       \
    set[2] = *reinterpret_cast<const float4*>(pR1 + (off));           \
    set[3] = *reinterpret_cast<const float4*>(pR1 + (off) + 4);       \
  }
#define CVT(set, base)                                                          \
  {                                                                             \
    uint w0, w1, w2, w3;                                                        \
    asm("v_cvt_pk_bf16_f32 %0,%1,%2" : "=v"(w0) : "v"(set[0].x), "v"(set[0].y));\
    asm("v_cvt_pk_bf16_f32 %0,%1,%2" : "=v"(w1) : "v"(set[0].z), "v"(set[0].w));\
    asm("v_cvt_pk_bf16_f32 %0,%1,%2" : "=v"(w2) : "v"(set[1].x), "v"(set[1].y));\
    asm("v_cvt_pk_bf16_f32 %0,%1,%2" : "=v"(w3) : "v"(set[1].z), "v"(set[1].w));\
    *reinterpret_cast<uint4*>(lds + (base) + tid * 16) =                        \
        make_uint4(w0, w1, w2, w3);                                             \
    asm("v_cvt_pk_bf16_f32 %0,%1,%2" : "=v"(w0) : "v"(set[2].x), "v"(set[2].y));\
    asm("v_cvt_pk_bf16_f32 %0,%1,%2" : "=v"(w1) : "v"(set[2].z), "v"(set[2].w));\
    asm("v_cvt_pk_bf16_f32 %0,%1,%2" : "=v"(w2) : "v"(set[3].x), "v"(set[3].y));\
    asm("v_cvt_pk_bf16_f32 %0,%1,%2" : "=v"(w3) : "v"(set[3].z), "v"(set[3].w));\
    *reinterpret_cast<uint4*>(lds + (base) + 8192 + tid * 16) =                 \
        make_uint4(w0, w1, w2, w3);                                             \
  }
#define PH_SYNC()                                    \
  __builtin_amdgcn_s_barrier();                      \
  asm volatile("s_waitcnt lgkmcnt(0)" ::: "memory"); \
  SB0;
#define LDA(dst, p)                                                          \
  _Pragma("unroll") for (int i_ = 0; i_ < 4; ++i_) {                         \
    dst[i_][0] = *reinterpret_cast<const bf16x8*>((p) + i_ * 2048 + swz0);   \
    dst[i_][1] = *reinterpret_cast<const bf16x8*>((p) + i_ * 2048 + swz1);   \
  }
#define LDB(dst, p)                                                          \
  _Pragma("unroll") for (int j_ = 0; j_ < 2; ++j_) {                         \
    dst[j_][0] = *reinterpret_cast<const bf16x8*>((p) + j_ * 2048 + swz0);   \
    dst[j_][1] = *reinterpret_cast<const bf16x8*>((p) + j_ * 2048 + swz1);   \
  }

  // ---- prologue: buf0 <- Kt0 (A cvt + B stg), buf1 <- Kt1 (A cvt);
  // exit FIFO = [sa(4), B1stg(2), sb(4)] = 10 (steady entry pattern) ----
  AISS(sc, 0); SB0;
  AISS(sd, 131072); SB0;
  CVT(sc, 0); SB0;
  CVT(sd, 16384); SB0;
  AISS(sc, 64); SB0;
  AISS(sd, 131072 + 64); SB0;
  CVT(sc, 65536); SB0;
  CVT(sd, 81920); SB0;
  STG(bS0, bS1, 0, 32768); SB0;
  AISS(sa, 128); SB0;
  STG(bS2, bS3, 0, 49152); SB0;
  AISS(sb, 131072 + 128); SB0;
  asm volatile("s_waitcnt vmcnt(10)" ::: "memory");
  asm volatile("s_waitcnt lgkmcnt(0)" ::: "memory");
  __builtin_amdgcn_s_barrier();
  SB0;

#define ITER(M)                                                             \
  {                                                                         \
    const int ktB1 = (2 * it + 1) * 64;                                     \
    const int ktB2 = (2 * it + 2) * 64;                                     \
    const int offC = (2 * it + 3) * 64;                                     \
    const int offA2 = (2 * it + 4) * 64;                                    \
    /* ph1 */                                                               \
    LDA(aF, p0A); LDB(bF, p0B);                                             \
    STG(bS0, bS1, ktB1, 98304);                                             \
    PH_SYNC();                                                              \
    mfma16<0, 0>(acc, aF, bF);                                              \
    __builtin_amdgcn_s_barrier();                                           \
    /* ph2 */                                                               \
    if (M < 2) AISS(sc, offC);                                              \
    STG(bS2, bS3, ktB1, 114688);                                            \
    LDA(aG, p0A + 8192);                                                    \
    PH_SYNC();                                                              \
    mfma16<4, 0>(acc, aG, bF);                                              \
    SB0;                                                                    \
    if (M < 2) { asm volatile("s_waitcnt vmcnt(12)" ::: "memory"); }        \
    else       { asm volatile("s_waitcnt vmcnt(4)" ::: "memory"); }         \
    __builtin_amdgcn_s_barrier();                                           \
    SB0;                                                                    \
    /* ph3 */                                                               \
    if (M < 2) { CVT(sa, 0); CVT(sb, 16384); AISS(sd, 131072 + offC); }     \
    LDB(bG, p0B + 4096);                                                    \
    PH_SYNC();                                                              \
    mfma16<0, 2>(acc, aF, bG);                                              \
    __builtin_amdgcn_s_barrier();                                           \
    /* ph4 */                                                               \
    mfma16<4, 2>(acc, aG, bG);                                              \
    SB0;                                                                    \
    if (M < 2) { asm volatile("s_waitcnt vmcnt(10)" ::: "memory"); }        \
    else       { asm volatile("s_waitcnt vmcnt(2)" ::: "memory"); }         \
    __builtin_amdgcn_s_barrier();                                           \
    SB0;                                                                    \
    /* ph5 */                                                               \
    LDA(aF, p1A); LDB(bF, p1B);                                             \
    if (M < 2) STG(bS0, bS1, ktB2, 32768);                                  \
    PH_SYNC();                                                              \
    mfma16<0, 0>(acc, aF, bF);                                              \
    __builtin_amdgcn_s_barrier();                                           \
    /* ph6 */                                                               \
    if (M == 0) AISS(sa, offA2);                                            \
    if (M < 2) STG(bS2, bS3, ktB2, 49152);                                  \
    LDA(aG, p1A + 8192);                                                    \
    PH_SYNC();                                                              \
    mfma16<4, 0>(acc, aG, bF);                                              \
    SB0;                                                                    \
    if (M == 0)      { asm volatile("s_waitcnt vmcnt(12)" ::: "memory"); }  \
    else if (M == 1) { asm volatile("s_waitcnt vmcnt(8)" ::: "memory"); }   \
    else             { asm volatile("s_waitcnt vmcnt(0)" ::: "memory"); }   \
    __builtin_amdgcn_s_barrier();                                           \
    SB0;                                                                    \
    /* ph7 */                                                               \
    if (M < 2) { CVT(sc, 65536); CVT(sd, 81920); }                          \
    if (M == 0) AISS(sb, 131072 + offA2);                                   \
    LDB(bG, p1B + 4096);                                                    \
    PH_SYNC();                                                              \
    mfma16<0, 2>(acc, aF, bG);                                              \
    __builtin_amdgcn_s_barrier();                                           \
    /* ph8 */                                                               \
    mfma16<4, 2>(acc, aG, bG);                                              \
    if (M == 0) {                                                           \
      SB0;                                                                  \
      asm volatile("s_waitcnt vmcnt(10)" ::: "memory");                     \
      __builtin_amdgcn_s_barrier();                                         \
      SB0;                                                                  \
    } else if (M == 1) {                                                    \
      SB0;                                                                  \
      asm volatile("s_waitcnt vmcnt(2)" ::: "memory");                      \
      __builtin_amdgcn_s_barrier();                                         \
      SB0;                                                                  \
    }                                                                       \
  }

#pragma unroll 1
  for (int it = 0; it < 6; ++it) ITER(0);
  { const int it = 6; ITER(1); }
  { const int it = 7; ITER(2); }
#undef ITER
#undef STG
#undef AISS
#undef CVT
#undef PH_SYNC
#undef LDA
#undef LDB
#undef SB0

  // ---- epilogue: C/D layout col=lane&15, row=(lane>>4)*4+r ----
#pragma unroll
  for (int fi = 0; fi < 8; ++fi) {
#pragma unroll
    for (int fj = 0; fj < 4; ++fj) {
      int n = bn * 256 + wn * 64 + fj * 16 + lm;
      float bv = bias[n];
#pragma unroll
      for (int r = 0; r < 4; ++r) {
        size_t m = bm * 256 + wm * 128 + fi * 16 + ((lane >> 4) * 4) + r;
        Cg[m * 1024 + n] = f2bf(acc[fi][fj][r] + bv);
      }
    }
  }
}

// ---------------- 128x128 gload_lds GEMM (Q/O; verified) -------------------
template <typename TOUT>
__global__ __launch_bounds__(256) void gemm_lds(const ushort* __restrict__ Ag,
                                                const ushort* __restrict__ Wg,
                                                const float* __restrict__ bias,
                                                TOUT* __restrict__ Cg) {
  constexpr int K = 1024;
  __shared__ ushort lA[128 * 64];
  __shared__ ushort lB[128 * 64];
  const int tid = threadIdx.x;
  const int lane = tid & 63;
  const int wave = tid >> 6;
  const int wr = (wave >> 1) * 64;
  const int wc = (wave & 1) * 64;
  const int d = blockIdx.x;
  const int bn = (d >> 3) & 7;
  const size_t bm = (size_t)(d & 7) * (gridDim.x >> 6) + (d >> 6);

  const ushort* aB = Ag + bm * 128 * K;
  const ushort* bB = Wg + (size_t)bn * 128 * K;
  const int srow = wave * 32 + (lane >> 3);
  const int scol = ((lane & 7) ^ (lane >> 3)) * 8;
  char* lAc = (char*)lA;
  char* lBc = (char*)lB;

  f32x4 acc[4][4] = {};

  for (int kt = 0; kt < K; kt += 64) {
    __syncthreads();
#pragma unroll
    for (int c = 0; c < 4; ++c) {
      __builtin_amdgcn_global_load_lds(
          (gvp)(aB + (size_t)(srow + c * 8) * K + kt + scol),
          (lvp)(lAc + wave * 4096 + c * 1024), 16, 0, 0);
      __builtin_amdgcn_global_load_lds(
          (gvp)(bB + (size_t)(srow + c * 8) * K + kt + scol),
          (lvp)(lBc + wave * 4096 + c * 1024), 16, 0, 0);
    }
    __syncthreads();
#pragma unroll
    for (int kk = 0; kk < 2; ++kk) {
      bf16x8 af[4], bg[4];
#pragma unroll
      for (int fi = 0; fi < 4; ++fi) {
        int r = wr + fi * 16 + (lane & 15);
        int byte = (r * 128 + kk * 64 + ((lane >> 4) * 16)) ^ ((r & 7) << 4);
        af[fi] = *reinterpret_cast<const bf16x8*>(lAc + byte);
      }
#pragma unroll
      for (int fj = 0; fj < 4; ++fj) {
        int r = wc + fj * 16 + (lane & 15);
        int byte = (r * 128 + kk * 64 + ((lane >> 4) * 16)) ^ ((r & 7) << 4);
        bg[fj] = *reinterpret_cast<const bf16x8*>(lBc + byte);
      }
#pragma unroll
      for (int fi = 0; fi < 4; ++fi)
#pragma unroll
        for (int fj = 0; fj < 4; ++fj)
          acc[fi][fj] = __builtin_amdgcn_mfma_f32_16x16x32_bf16(af[fi], bg[fj],
                                                                acc[fi][fj], 0, 0, 0);
    }
  }
#pragma unroll
  for (int fi = 0; fi < 4; ++fi) {
#pragma unroll
    for (int fj = 0; fj < 4; ++fj) {
      int n = bn * 128 + wc + fj * 16 + (lane & 15);
      float bv = bias[n];
#pragma unroll
      for (int r = 0; r < 4; ++r) {
        size_t m = bm * 128 + wr + fi * 16 + ((lane >> 4) * 4) + r;
        float val = acc[fi][fj][r] + bv;
        if constexpr (sizeof(TOUT) == 2)
          reinterpret_cast<ushort*>(Cg)[m * 1024 + n] = f2bf(val);
        else
          reinterpret_cast<float*>(Cg)[m * 1024 + n] = val;
      }
    }
  }
}

// ------------- reg-staged GEMM (fp32 A): fallback path only ---------------
template <typename TIN, typename TOUT>
__global__ __launch_bounds__(256) void gemm_bias(const TIN* __restrict__ Ag,
                                                 const float* __restrict__ Wg,
                                                 const float* __restrict__ bias,
                                                 TOUT* __restrict__ Cg) {
  constexpr int K = 1024;
  __shared__ char lA[128 * 64 * 2];
  __shared__ char lB[128 * 64 * 2];
  const int tid = threadIdx.x;
  const int lane = tid & 63;
  const int wave = tid >> 6;
  const int wr = (wave >> 1) * 64;
  const int wc = (wave & 1) * 64;
  const int bn = blockIdx.x;
  const size_t bm = blockIdx.y;

  const TIN* aBase = Ag + bm * 128 * K;
  const float* bBase = Wg + (size_t)bn * 128 * K;

  f32x4 acc[4][4] = {};

  for (int kt = 0; kt < K; kt += 64) {
    __syncthreads();
    if constexpr (sizeof(TIN) == 4) {
#pragma unroll
      for (int i = 0; i < 8; ++i) {
        int f = tid + i * 256;
        int row = f >> 4, c4 = f & 15;
        const float4 v = *reinterpret_cast<const float4*>(
            reinterpret_cast<const float*>(aBase) + (size_t)row * K + kt + c4 * 4);
        ushort4 pk;
        pk.x = f2bf(v.x); pk.y = f2bf(v.y); pk.z = f2bf(v.z); pk.w = f2bf(v.w);
        int byte = (row * 128 + c4 * 8) ^ ((row & 7) << 4);
        *reinterpret_cast<ushort4*>(lA + byte) = pk;
      }
    } else {
#pragma unroll
      for (int i = 0; i < 4; ++i) {
        int f = tid + i * 256;
        int row = f >> 3, c8 = f & 7;
        int4 v = *reinterpret_cast<const int4*>(
            reinterpret_cast<const ushort*>(aBase) + (size_t)row * K + kt + c8 * 8);
        int byte = (row * 128 + c8 * 16) ^ ((row & 7) << 4);
        *reinterpret_cast<int4*>(lA + byte) = v;
      }
    }
#pragma unroll
    for (int i = 0; i < 8; ++i) {
      int f = tid + i * 256;
      int row = f >> 4, c4 = f & 15;
      const float4 v =
          *reinterpret_cast<const float4*>(bBase + (size_t)row * K + kt + c4 * 4);
      ushort4 pk;
      pk.x = f2bf(v.x); pk.y = f2bf(v.y); pk.z = f2bf(v.z); pk.w = f2bf(v.w);
      int byte = (row * 128 + c4 * 8) ^ ((row & 7) << 4);
      *reinterpret_cast<ushort4*>(lB + byte) = pk;
    }
    __syncthreads();
#pragma unroll
    for (int kk = 0; kk < 2; ++kk) {
      bf16x8 af[4], bg[4];
#pragma unroll
      for (int fi = 0; fi < 4; ++fi) {
        int r = wr + fi * 16 + (lane & 15);
        int byte = (r * 128 + kk * 64 + ((lane >> 4) * 16)) ^ ((r & 7) << 4);
        af[fi] = *reinterpret_cast<const bf16x8*>(lA + byte);
      }
#pragma unroll
      for (int fj = 0; fj < 4; ++fj) {
        int r = wc + fj * 16 + (lane & 15);
        int byte = (r * 128 + kk * 64 + ((lane >> 4) * 16)) ^ ((r & 7) << 4);
        bg[fj] = *reinterpret_cast<const bf16x8*>(lB + byte);
      }
#pragma unroll
      for (int fi = 0; fi < 4; ++fi)
#pragma unroll
        for (int fj = 0; fj < 4; ++fj)
          acc[fi][fj] =
              __builtin_amdgcn_mfma_f32_16x16x32_bf16(af[fi], bg[fj], acc[fi][fj], 0, 0, 0);
    }
  }
#pragma unroll
  for (int fi = 0; fi < 4; ++fi) {
#pragma unroll
    for (int fj = 0; fj < 4; ++fj) {
      int n = bn * 128 + wc + fj * 16 + (lane & 15);
      float bv = bias[n];
#pragma unroll
      for (int r = 0; r < 4; ++r) {
        size_t m = bm * 128 + wr + fi * 16 + ((lane >> 4) * 4) + r;
        float val = acc[fi][fj][r] + bv;
        if constexpr (sizeof(TOUT) == 2)
          reinterpret_cast<ushort*>(Cg)[m * 1024 + n] = f2bf(val);
        else
          reinterpret_cast<float*>(Cg)[m * 1024 + n] = val;
      }
    }
  }
}

// ---------------- attention: one block per (b,s'), head-axis softmax ------
__global__ __launch_bounds__(512) void attn_kernel(const ushort* __restrict__ Q,
                                                   const ushort* __restrict__ Kl,
                                                   const ushort* __restrict__ Vl,
                                                   ushort* __restrict__ Aout) {
  const int bs = blockIdx.x;
  const int b = bs >> 11, sp = bs & 2047;
  const int tid = threadIdx.x;
  const int wave = tid >> 6, lane = tid & 63;

  __shared__ ushort qrow[1024];
  __shared__ float sc[16][32];
  __shared__ float attnw[16][32];
  __shared__ float mx[32], rinv[32];

  reinterpret_cast<uint*>(qrow)[tid] =
      reinterpret_cast<const uint*>(Q + (size_t)bs * 1024)[tid];
  __syncthreads();

  const int wp = lane & 31, half = lane >> 5;
#pragma unroll
  for (int hh = 0; hh < 2; ++hh) {
    const int h = wave * 2 + hh;
    const int s_k = h * 128 + (sp >> 4);
    const int w_k = (sp & 15) * 2 + (wp >> 4);
    const ushort* kp =
        Kl + (((size_t)(b * 2048 + s_k) * 32) + w_k) * 1024 + (wp & 15) * 64 + half * 32;
    const ushort* qp = qrow + h * 64 + half * 32;
    float dot = 0.f;
#pragma unroll
    for (int j = 0; j < 32; j += 8) {
      int4 kv = *reinterpret_cast<const int4*>(kp + j);
      int4 qv = *reinterpret_cast<const int4*>(qp + j);
      const ushort* ka = reinterpret_cast<const ushort*>(&kv);
      const ushort* qa = reinterpret_cast<const ushort*>(&qv);
#pragma unroll
      for (int t = 0; t < 8; ++t) dot += bf2f(ka[t]) * bf2f(qa[t]);
    }
    dot += __shfl_xor(dot, 32);
    if (half == 0) sc[h][wp] = dot * 0.125f;
  }
  __syncthreads();
  if (tid < 32) {
    float m = sc[0][tid];
#pragma unroll
    for (int h = 1; h < 16; ++h) m = fmaxf(m, sc[h][tid]);
    float s = 0.f;
#pragma unroll
    for (int h = 0; h < 16; ++h) s += __expf(sc[h][tid] - m);
    mx[tid] = m;
    rinv[tid] = 1.f / s;
  }
  __syncthreads();
  if (lane < 32) {
#pragma unroll
    for (int hh = 0; hh < 2; ++hh) {
      const int h = wave * 2 + hh;
      attnw[h][lane] = __expf(sc[h][lane] - mx[lane]) * rinv[lane];
    }
  }
  __syncthreads();
#pragma unroll
  for (int hh = 0; hh < 2; ++hh) {
    const int h = wave * 2 + hh;
    const int s_k = h * 128 + (sp >> 4);
    const size_t vb = (((size_t)(b * 2048 + s_k) * 32) + (sp & 15) * 2) * 1024;
    float a = 0.f;
#pragma unroll
    for (int w2 = 0; w2 < 32; ++w2) {
      float wgt = attnw[h][w2];
      a += wgt * bf2f(Vl[vb + (size_t)(w2 >> 4) * 1024 + (w2 & 15) * 64 + lane]);
    }
    Aout[(((size_t)(b * 16 + h)) * 2048 + sp) * 64 + lane] = f2bf(a);
  }
}

extern "C" void kernel_launch(void* const* d_in, const int* in_sizes, int n_in,
                              void* d_out, int out_size, void* d_ws, size_t ws_size,
                              hipStream_t stream) {
  const float* q = (const float*)d_in[0];
  const float* k = (const float*)d_in[1];
  const float* v = (const float*)d_in[2];
  const float* Wq = (const float*)d_in[3];
  const float* bq = (const float*)d_in[4];
  const float* Wk = (const float*)d_in[5];
  const float* bk = (const float*)d_in[6];
  const float* Wv = (const float*)d_in[7];
  const float* bv = (const float*)d_in[8];
  const float* Wo = (const float*)d_in[9];
  const float* bo = (const float*)d_in[10];
  float* out = (float*)d_out;

  char* ws = (char*)d_ws;
  const size_t MB = 1u << 20;
  ushort* Qlin = (ushort*)ws;                    // 8 MiB
  ushort* Aws  = (ushort*)(ws + 8 * MB);         // 8 MiB
  ushort* wkbf = (ushort*)(ws + 16 * MB);        // 2 MiB
  ushort* wvbf = (ushort*)(ws + 18 * MB);        // 2 MiB
  ushort* wqbf = (ushort*)(ws + 20 * MB);        // 2 MiB
  ushort* wobf = (ushort*)(ws + 22 * MB);        // 2 MiB
  ushort* qbf  = (ushort*)(ws + 24 * MB);        // 8 MiB
  ushort* Klin = (ushort*)(ws + 32 * MB);        // 256 MiB
  ushort* Vlin = (ushort*)(ws + 288 * MB);       // 256 MiB
  const bool full = ws_size >= 800 * MB;

  if (full) {
    cast_kernel<<<dim3(512), 256, 0, stream>>>(Wq, wqbf, 1048576L);
    cast_kernel<<<dim3(512), 256, 0, stream>>>(Wk, wkbf, 1048576L);
    cast_kernel<<<dim3(512), 256, 0, stream>>>(Wv, wvbf, 1048576L);
    cast_kernel<<<dim3(512), 256, 0, stream>>>(Wo, wobf, 1048576L);
    cast_kernel<<<dim3(2048), 256, 0, stream>>>(q, qbf, 4194304L);
    gemm_lds<ushort><<<dim3(256), 256, 0, stream>>>(qbf, wqbf, bq, Qlin);
    gemm_big<<<dim3(2048), 512, 0, stream>>>(k, wkbf, bk, Klin);
    gemm_big<<<dim3(2048), 512, 0, stream>>>(v, wvbf, bv, Vlin);
    attn_kernel<<<dim3(4096), dim3(512), 0, stream>>>(Qlin, Klin, Vlin, Aws);
    gemm_lds<float><<<dim3(256), 256, 0, stream>>>(Aws, wobf, bo, out);
  } else {
    gemm_bias<float, ushort><<<dim3(8, 32), 256, 0, stream>>>(q, Wq, bq, Qlin);
    gemm_bias<float, ushort><<<dim3(8, 1024), 256, 0, stream>>>(k, Wk, bk, Klin);
    gemm_bias<float, ushort><<<dim3(8, 1024), 256, 0, stream>>>(v, Wv, bv, Vlin);
    attn_kernel<<<dim3(4096), dim3(512), 0, stream>>>(Qlin, Klin, Vlin, Aws);
    gemm_bias<ushort, float><<<dim3(8, 32), 256, 0, stream>>>(Aws, Wo, bo, out);
  }
}

// Round 4
// 2269.631 us; speedup vs baseline: 1.0016x; 1.0016x over previous
//
#include <hip/hip_runtime.h>
#include <hip/hip_bf16.h>

// B=2, S=2048, W=32, D=1024, H=16, hd=64
// Pipeline (full path):
//   bf16-cast: Wq,Wk,Wv,Wo,q (small only)
//   K/V GEMM: gemm_big = 256x256 tile, BK=64, 8-phase schedule with FUSED
//             fp32->bf16 A-cast. A: reg-staged (4x global_load_dwordx4
//             issued 5 phases ahead -> v_cvt_pk_bf16_f32 -> swizzled
//             ds_write_b128, CVTs ONLY in ph3 (buf0) / ph7 (buf1) after all
//             reads of that region complete). B: global_load_lds.
//             ALL vmcnt drains at phase END followed by s_barrier.
//             __launch_bounds__(512,1): LDS=128KiB means 1 block/CU is the
//             hardware max regardless; promising 2 capped VGPRs at 128 and
//             caused catastrophic scratch spills (round-3 post-mortem:
//             WRITE_SIZE 1.68GB vs 0.27GB ideal). With 1: 256-VGPR budget,
//             no spills, same occupancy.
//   Q/O GEMM: gemm_lds (128x128)
//   attn: per (b,s') head-softmax gather-attention -> A (4096x1024 bf16)
//   out  = A@Wo^T+bo (fp32)

#define DEVI __device__ __forceinline__

typedef __attribute__((ext_vector_type(8))) short bf16x8;
typedef __attribute__((ext_vector_type(4))) float f32x4;
typedef const __attribute__((address_space(1))) void* gvp;
typedef __attribute__((address_space(3))) void* lvp;

DEVI ushort f2bf(float f) {
  uint u = __float_as_uint(f);
  u = u + 0x7fffu + ((u >> 16) & 1u);
  return (ushort)(u >> 16);
}
DEVI float bf2f(ushort u) { return __uint_as_float(((uint)u) << 16); }

// ---------------- elementwise fp32 -> bf16 cast (RNE), 8 elems/thread ----
__global__ __launch_bounds__(256) void cast_kernel(const float* __restrict__ in,
                                                   ushort* __restrict__ out,
                                                   long n) {
  long i = ((long)blockIdx.x * 256 + threadIdx.x) * 8;
  const long stride = (long)gridDim.x * 256 * 8;
  for (; i < n; i += stride) {
    float4 a = *reinterpret_cast<const float4*>(in + i);
    float4 b = *reinterpret_cast<const float4*>(in + i + 4);
    ushort o[8];
    o[0] = f2bf(a.x); o[1] = f2bf(a.y); o[2] = f2bf(a.z); o[3] = f2bf(a.w);
    o[4] = f2bf(b.x); o[5] = f2bf(b.y); o[6] = f2bf(b.z); o[7] = f2bf(b.w);
    *reinterpret_cast<int4*>(out + i) = *reinterpret_cast<const int4*>(o);
  }
}

// ---------------- fused-cast 8-phase GEMM: C = A(fp32) @ W(bf16)^T + bias --
// Tile 256(M)x256(N), K=1024, BK=64, 16 K-tiles, 8 iters x 2 tiles.
// LDS (bf16): buf0: A0@0 A1@16K B0@32K B1@48K; buf1 = +64K. Each half =
// 128 rows x 64 cols (row 128B = 8 chunks of 16B); stored chunk p of row r
// holds source chunk p^(r&7); read swz ((kk*4+q)^(lm&7))*16.
// Schedule (j = 2*it; steady M=0):
//  ph1: LDA aF, LDB bF (buf0)      STG B0(j+1)->buf1.B0          mfma<0,0>
//  ph2: AISS sc=A0(j+3)            STG B1(j+1)->buf1.B1  LDA aG  mfma<4,0>
//       end: vmcnt(12)+bar   [buf0.B1(j) resident for ph3]
//  ph3: CVT sa->buf0.A0(j+2) CVT sb->buf0.A1(j+2) AISS sd=A1(j+3) LDB bG
//                                                                mfma<0,2>
//  ph4:                                                          mfma<4,2>
//       end: vmcnt(10)+bar   [buf1.B0(j+1) resident for ph5]
//  ph5: LDA aF, LDB bF (buf1)      STG B0(j+2)->buf0.B0          mfma<0,0>
//  ph6: AISS sa=A0(j+4)            STG B1(j+2)->buf0.B1  LDA aG  mfma<4,0>
//       end: vmcnt(12)+bar   [buf1.B1(j+1) resident for ph7]
//  ph7: CVT sc->buf1.A0(j+3) CVT sd->buf1.A1(j+3) AISS sb=A1(j+4) LDB bG
//                                                                mfma<0,2>
//  ph8:                                                          mfma<4,2>
//       end: vmcnt(10)+bar   [buf0.B0(j+2) resident for next ph1]
// Region safety: buf.A last read in ph2/ph6 (aG) -> written in ph3/ph7;
// CVT visibility via writer's lgkmcnt(0) (PH_SYNC) + barriers.
// Tails: it6 (M=1) skips AISS sa/sb (drains 12/10/8/2);
//        it7 (M=2) skips all AISS/CVT + ph5/ph6 STGs (drains 4/2/0/-).
template <int FI0, int FJ0>
DEVI void mfma16(f32x4 (&acc)[8][4], const bf16x8 (&A)[4][2],
                 const bf16x8 (&B)[2][2]) {
  __builtin_amdgcn_s_setprio(1);
#pragma unroll
  for (int i = 0; i < 4; ++i)
#pragma unroll
    for (int j = 0; j < 2; ++j)
#pragma unroll
      for (int kk = 0; kk < 2; ++kk)
        acc[FI0 + i][FJ0 + j] = __builtin_amdgcn_mfma_f32_16x16x32_bf16(
            A[i][kk], B[j][kk], acc[FI0 + i][FJ0 + j], 0, 0, 0);
  __builtin_amdgcn_s_setprio(0);
}

__global__ __launch_bounds__(512, 1) void gemm_big(const float* __restrict__ Ag,
                                                   const ushort* __restrict__ Wg,
                                                   const float* __restrict__ bias,
                                                   ushort* __restrict__ Cg) {
  constexpr int K = 1024;
  __shared__ char lds[131072];
  const int tid = threadIdx.x;
  const int lane = tid & 63;
  const int wave = tid >> 6;
  const int wm = wave >> 2;
  const int wn = wave & 3;
  const int d = blockIdx.x;
  const int bn = (d >> 3) & 3;
  const size_t bm = (size_t)(d & 7) * (gridDim.x >> 5) + (d >> 5);

  const ushort* bB = Wg + (size_t)bn * 256 * K;

  // staging geometry: chunk f=tid -> row r0=tid>>3, pos tid&7; source chunk
  // c0=(tid&7)^(r0&7) (same for r0+64k). A is fp32: chunk = 8 floats.
  const int r0 = tid >> 3;
  const int c0 = (tid & 7) ^ (r0 & 7);
  const float* pR0 = Ag + bm * 256 * K + (size_t)r0 * K + c0 * 8;
  const float* pR1 = pR0 + 64 * K;
  const ushort* bS0 = bB + (size_t)r0 * K + c0 * 8;
  const ushort* bS1 = bB + (size_t)(r0 + 64) * K + c0 * 8;
  const ushort* bS2 = bB + (size_t)(r0 + 128) * K + c0 * 8;
  const ushort* bS3 = bB + (size_t)(r0 + 192) * K + c0 * 8;

  // fragment-read offsets
  const int lm = lane & 15;
  const int q = lane >> 4;
  const int rowB = lm * 128;
  const int swz0 = (q ^ (lm & 7)) * 16;
  const int swz1 = ((4 + q) ^ (lm & 7)) * 16;
  const char* ldsc = (const char*)lds;
  const char* p0A = ldsc + wm * 16384 + rowB;
  const char* p0B = ldsc + 32768 + (wn >> 1) * 16384 + (wn & 1) * 8192 + rowB;
  const char* p1A = p0A + 65536;
  const char* p1B = p0B + 65536;

  f32x4 acc[8][4] = {};
  bf16x8 aF[4][2], aG[4][2], bF[2][2], bG[2][2];
  float4 sa[4], sb[4], sc[4], sd[4];

#define SB0 __builtin_amdgcn_sched_barrier(0)
#define STG(p0, p1, ktE, ldsOff)                                                 \
  {                                                                              \
    __builtin_amdgcn_global_load_lds((gvp)((p0) + (ktE)),                        \
                                     (lvp)(lds + (ldsOff) + tid * 16), 16, 0, 0);\
    __builtin_amdgcn_global_load_lds((gvp)((p1) + (ktE)),                        \
                                     (lvp)(lds + (ldsOff) + 8192 + tid * 16),    \
                                     16, 0, 0);                                  \
  }
#define AISS(set, off)                                                \
  {                                                                   \
    set[0] = *reinterpret_cast<const float4*>(pR0 + (off));           \
    set[1] = *reinterpret_cast<const float4*>(pR0 + (off) + 4);       \
    set[2] = *reinterpret_cast<const float4*>(pR1 + (off));           \
    set[3] = *reinterpret_cast<const float4*>(pR1 + (off) + 4);       \
  }
#define CVT(set, base)                                                          \
  {                                                                             \
    uint w0, w1, w2, w3;                                                        \
    asm("v_cvt_pk_bf16_f32 %0,%1,%2" : "=v"(w0) : "v"(set[0].x), "v"(set[0].y));\
    asm("v_cvt_pk_bf16_f32 %0,%1,%2" : "=v"(w1) : "v"(set[0].z), "v"(set[0].w));\
    asm("v_cvt_pk_bf16_f32 %0,%1,%2" : "=v"(w2) : "v"(set[1].x), "v"(set[1].y));\
    asm("v_cvt_pk_bf16_f32 %0,%1,%2" : "=v"(w3) : "v"(set[1].z), "v"(set[1].w));\
    *reinterpret_cast<uint4*>(lds + (base) + tid * 16) =                        \
        make_uint4(w0, w1, w2, w3);                                             \
    asm("v_cvt_pk_bf16_f32 %0,%1,%2" : "=v"(w0) : "v"(set[2].x), "v"(set[2].y));\
    asm("v_cvt_pk_bf16_f32 %0,%1,%2" : "=v"(w1) : "v"(set[2].z), "v"(set[2].w));\
    asm("v_cvt_pk_bf16_f32 %0,%1,%2" : "=v"(w2) : "v"(set[3].x), "v"(set[3].y));\
    asm("v_cvt_pk_bf16_f32 %0,%1,%2" : "=v"(w3) : "v"(set[3].z), "v"(set[3].w));\
    *reinterpret_cast<uint4*>(lds + (base) + 8192 + tid * 16) =                 \
        make_uint4(w0, w1, w2, w3);                                             \
  }
#define PH_SYNC()                                    \
  __builtin_amdgcn_s_barrier();                      \
  asm volatile("s_waitcnt lgkmcnt(0)" ::: "memory"); \
  SB0;
#define LDA(dst, p)                                                          \
  _Pragma("unroll") for (int i_ = 0; i_ < 4; ++i_) {                         \
    dst[i_][0] = *reinterpret_cast<const bf16x8*>((p) + i_ * 2048 + swz0);   \
    dst[i_][1] = *reinterpret_cast<const bf16x8*>((p) + i_ * 2048 + swz1);   \
  }
#define LDB(dst, p)                                                          \
  _Pragma("unroll") for (int j_ = 0; j_ < 2; ++j_) {                         \
    dst[j_][0] = *reinterpret_cast<const bf16x8*>((p) + j_ * 2048 + swz0);   \
    dst[j_][1] = *reinterpret_cast<const bf16x8*>((p) + j_ * 2048 + swz1);   \
  }

  // ---- prologue: buf0 <- Kt0 (A cvt + B stg), buf1 <- Kt1 (A cvt);
  // exit FIFO = [sa(4), B1stg(2), sb(4)] = 10 (steady entry pattern) ----
  AISS(sc, 0); SB0;
  AISS(sd, 131072); SB0;
  CVT(sc, 0); SB0;
  CVT(sd, 16384); SB0;
  AISS(sc, 64); SB0;
  AISS(sd, 131072 + 64); SB0;
  CVT(sc, 65536); SB0;
  CVT(sd, 81920); SB0;
  STG(bS0, bS1, 0, 32768); SB0;
  AISS(sa, 128); SB0;
  STG(bS2, bS3, 0, 49152); SB0;
  AISS(sb, 131072 + 128); SB0;
  asm volatile("s_waitcnt vmcnt(10)" ::: "memory");
  asm volatile("s_waitcnt lgkmcnt(0)" ::: "memory");
  __builtin_amdgcn_s_barrier();
  SB0;

#define ITER(M)                                                             \
  {                                                                         \
    const int ktB1 = (2 * it + 1) * 64;                                     \
    const int ktB2 = (2 * it + 2) * 64;                                     \
    const int offC = (2 * it + 3) * 64;                                     \
    const int offA2 = (2 * it + 4) * 64;                                    \
    /* ph1 */                                                               \
    LDA(aF, p0A); LDB(bF, p0B);                                             \
    STG(bS0, bS1, ktB1, 98304);                                             \
    PH_SYNC();                                                              \
    mfma16<0, 0>(acc, aF, bF);                                              \
    __builtin_amdgcn_s_barrier();                                           \
    /* ph2 */                                                               \
    if (M < 2) AISS(sc, offC);                                              \
    STG(bS2, bS3, ktB1, 114688);                                            \
    LDA(aG, p0A + 8192);                                                    \
    PH_SYNC();                                                              \
    mfma16<4, 0>(acc, aG, bF);                                              \
    SB0;                                                                    \
    if (M < 2) { asm volatile("s_waitcnt vmcnt(12)" ::: "memory"); }        \
    else       { asm volatile("s_waitcnt vmcnt(4)" ::: "memory"); }         \
    __builtin_amdgcn_s_barrier();                                           \
    SB0;                                                                    \
    /* ph3 */                                                               \
    if (M < 2) { CVT(sa, 0); CVT(sb, 16384); AISS(sd, 131072 + offC); }     \
    LDB(bG, p0B + 4096);                                                    \
    PH_SYNC();                                                              \
    mfma16<0, 2>(acc, aF, bG);                                              \
    __builtin_amdgcn_s_barrier();                                           \
    /* ph4 */                                                               \
    mfma16<4, 2>(acc, aG, bG);                                              \
    SB0;                                                                    \
    if (M < 2) { asm volatile("s_waitcnt vmcnt(10)" ::: "memory"); }        \
    else       { asm volatile("s_waitcnt vmcnt(2)" ::: "memory"); }         \
    __builtin_amdgcn_s_barrier();                                           \
    SB0;                                                                    \
    /* ph5 */                                                               \
    LDA(aF, p1A); LDB(bF, p1B);                                             \
    if (M < 2) STG(bS0, bS1, ktB2, 32768);                                  \
    PH_SYNC();                                                              \
    mfma16<0, 0>(acc, aF, bF);                                              \
    __builtin_amdgcn_s_barrier();                                           \
    /* ph6 */                                                               \
    if (M == 0) AISS(sa, offA2);                                            \
    if (M < 2) STG(bS2, bS3, ktB2, 49152);                                  \
    LDA(aG, p1A + 8192);                                                    \
    PH_SYNC();                                                              \
    mfma16<4, 0>(acc, aG, bF);                                              \
    SB0;                                                                    \
    if (M == 0)      { asm volatile("s_waitcnt vmcnt(12)" ::: "memory"); }  \
    else if (M == 1) { asm volatile("s_waitcnt vmcnt(8)" ::: "memory"); }   \
    else             { asm volatile("s_waitcnt vmcnt(0)" ::: "memory"); }   \
    __builtin_amdgcn_s_barrier();                                           \
    SB0;                                                                    \
    /* ph7 */                                                               \
    if (M < 2) { CVT(sc, 65536); CVT(sd, 81920); }                          \
    if (M == 0) AISS(sb, 131072 + offA2);                                   \
    LDB(bG, p1B + 4096);                                                    \
    PH_SYNC();                                                              \
    mfma16<0, 2>(acc, aF, bG);                                              \
    __builtin_amdgcn_s_barrier();                                           \
    /* ph8 */                                                               \
    mfma16<4, 2>(acc, aG, bG);                                              \
    if (M == 0) {                                                           \
      SB0;                                                                  \
      asm volatile("s_waitcnt vmcnt(10)" ::: "memory");                     \
      __builtin_amdgcn_s_barrier();                                         \
      SB0;                                                                  \
    } else if (M == 1) {                                                    \
      SB0;                                                                  \
      asm volatile("s_waitcnt vmcnt(2)" ::: "memory");                      \
      __builtin_amdgcn_s_barrier();                                         \
      SB0;                                                                  \
    }                                                                       \
  }

#pragma unroll 1
  for (int it = 0; it < 6; ++it) ITER(0);
  { const int it = 6; ITER(1); }
  { const int it = 7; ITER(2); }
#undef ITER
#undef STG
#undef AISS
#undef CVT
#undef PH_SYNC
#undef LDA
#undef LDB
#undef SB0

  // ---- epilogue: C/D layout col=lane&15, row=(lane>>4)*4+r ----
#pragma unroll
  for (int fi = 0; fi < 8; ++fi) {
#pragma unroll
    for (int fj = 0; fj < 4; ++fj) {
      int n = bn * 256 + wn * 64 + fj * 16 + lm;
      float bv = bias[n];
#pragma unroll
      for (int r = 0; r < 4; ++r) {
        size_t m = bm * 256 + wm * 128 + fi * 16 + ((lane >> 4) * 4) + r;
        Cg[m * 1024 + n] = f2bf(acc[fi][fj][r] + bv);
      }
    }
  }
}

// ---------------- 128x128 gload_lds GEMM (Q/O; verified) -------------------
template <typename TOUT>
__global__ __launch_bounds__(256) void gemm_lds(const ushort* __restrict__ Ag,
                                                const ushort* __restrict__ Wg,
                                                const float* __restrict__ bias,
                                                TOUT* __restrict__ Cg) {
  constexpr int K = 1024;
  __shared__ ushort lA[128 * 64];
  __shared__ ushort lB[128 * 64];
  const int tid = threadIdx.x;
  const int lane = tid & 63;
  const int wave = tid >> 6;
  const int wr = (wave >> 1) * 64;
  const int wc = (wave & 1) * 64;
  const int d = blockIdx.x;
  const int bn = (d >> 3) & 7;
  const size_t bm = (size_t)(d & 7) * (gridDim.x >> 6) + (d >> 6);

  const ushort* aB = Ag + bm * 128 * K;
  const ushort* bB = Wg + (size_t)bn * 128 * K;
  const int srow = wave * 32 + (lane >> 3);
  const int scol = ((lane & 7) ^ (lane >> 3)) * 8;
  char* lAc = (char*)lA;
  char* lBc = (char*)lB;

  f32x4 acc[4][4] = {};

  for (int kt = 0; kt < K; kt += 64) {
    __syncthreads();
#pragma unroll
    for (int c = 0; c < 4; ++c) {
      __builtin_amdgcn_global_load_lds(
          (gvp)(aB + (size_t)(srow + c * 8) * K + kt + scol),
          (lvp)(lAc + wave * 4096 + c * 1024), 16, 0, 0);
      __builtin_amdgcn_global_load_lds(
          (gvp)(bB + (size_t)(srow + c * 8) * K + kt + scol),
          (lvp)(lBc + wave * 4096 + c * 1024), 16, 0, 0);
    }
    __syncthreads();
#pragma unroll
    for (int kk = 0; kk < 2; ++kk) {
      bf16x8 af[4], bg[4];
#pragma unroll
      for (int fi = 0; fi < 4; ++fi) {
        int r = wr + fi * 16 + (lane & 15);
        int byte = (r * 128 + kk * 64 + ((lane >> 4) * 16)) ^ ((r & 7) << 4);
        af[fi] = *reinterpret_cast<const bf16x8*>(lAc + byte);
      }
#pragma unroll
      for (int fj = 0; fj < 4; ++fj) {
        int r = wc + fj * 16 + (lane & 15);
        int byte = (r * 128 + kk * 64 + ((lane >> 4) * 16)) ^ ((r & 7) << 4);
        bg[fj] = *reinterpret_cast<const bf16x8*>(lBc + byte);
      }
#pragma unroll
      for (int fi = 0; fi < 4; ++fi)
#pragma unroll
        for (int fj = 0; fj < 4; ++fj)
          acc[fi][fj] = __builtin_amdgcn_mfma_f32_16x16x32_bf16(af[fi], bg[fj],
                                                                acc[fi][fj], 0, 0, 0);
    }
  }
#pragma unroll
  for (int fi = 0; fi < 4; ++fi) {
#pragma unroll
    for (int fj = 0; fj < 4; ++fj) {
      int n = bn * 128 + wc + fj * 16 + (lane & 15);
      float bv = bias[n];
#pragma unroll
      for (int r = 0; r < 4; ++r) {
        size_t m = bm * 128 + wr + fi * 16 + ((lane >> 4) * 4) + r;
        float val = acc[fi][fj][r] + bv;
        if constexpr (sizeof(TOUT) == 2)
          reinterpret_cast<ushort*>(Cg)[m * 1024 + n] = f2bf(val);
        else
          reinterpret_cast<float*>(Cg)[m * 1024 + n] = val;
      }
    }
  }
}

// ------------- reg-staged GEMM (fp32 A): fallback path only ---------------
template <typename TIN, typename TOUT>
__global__ __launch_bounds__(256) void gemm_bias(const TIN* __restrict__ Ag,
                                                 const float* __restrict__ Wg,
                                                 const float* __restrict__ bias,
                                                 TOUT* __restrict__ Cg) {
  constexpr int K = 1024;
  __shared__ char lA[128 * 64 * 2];
  __shared__ char lB[128 * 64 * 2];
  const int tid = threadIdx.x;
  const int lane = tid & 63;
  const int wave = tid >> 6;
  const int wr = (wave >> 1) * 64;
  const int wc = (wave & 1) * 64;
  const int bn = blockIdx.x;
  const size_t bm = blockIdx.y;

  const TIN* aBase = Ag + bm * 128 * K;
  const float* bBase = Wg + (size_t)bn * 128 * K;

  f32x4 acc[4][4] = {};

  for (int kt = 0; kt < K; kt += 64) {
    __syncthreads();
    if constexpr (sizeof(TIN) == 4) {
#pragma unroll
      for (int i = 0; i < 8; ++i) {
        int f = tid + i * 256;
        int row = f >> 4, c4 = f & 15;
        const float4 v = *reinterpret_cast<const float4*>(
            reinterpret_cast<const float*>(aBase) + (size_t)row * K + kt + c4 * 4);
        ushort4 pk;
        pk.x = f2bf(v.x); pk.y = f2bf(v.y); pk.z = f2bf(v.z); pk.w = f2bf(v.w);
        int byte = (row * 128 + c4 * 8) ^ ((row & 7) << 4);
        *reinterpret_cast<ushort4*>(lA + byte) = pk;
      }
    } else {
#pragma unroll
      for (int i = 0; i < 4; ++i) {
        int f = tid + i * 256;
        int row = f >> 3, c8 = f & 7;
        int4 v = *reinterpret_cast<const int4*>(
            reinterpret_cast<const ushort*>(aBase) + (size_t)row * K + kt + c8 * 8);
        int byte = (row * 128 + c8 * 16) ^ ((row & 7) << 4);
        *reinterpret_cast<int4*>(lA + byte) = v;
      }
    }
#pragma unroll
    for (int i = 0; i < 8; ++i) {
      int f = tid + i * 256;
      int row = f >> 4, c4 = f & 15;
      const float4 v =
          *reinterpret_cast<const float4*>(bBase + (size_t)row * K + kt + c4 * 4);
      ushort4 pk;
      pk.x = f2bf(v.x); pk.y = f2bf(v.y); pk.z = f2bf(v.z); pk.w = f2bf(v.w);
      int byte = (row * 128 + c4 * 8) ^ ((row & 7) << 4);
      *reinterpret_cast<ushort4*>(lB + byte) = pk;
    }
    __syncthreads();
#pragma unroll
    for (int kk = 0; kk < 2; ++kk) {
      bf16x8 af[4], bg[4];
#pragma unroll
      for (int fi = 0; fi < 4; ++fi) {
        int r = wr + fi * 16 + (lane & 15);
        int byte = (r * 128 + kk * 64 + ((lane >> 4) * 16)) ^ ((r & 7) << 4);
        af[fi] = *reinterpret_cast<const bf16x8*>(lA + byte);
      }
#pragma unroll
      for (int fj = 0; fj < 4; ++fj) {
        int r = wc + fj * 16 + (lane & 15);
        int byte = (r * 128 + kk * 64 + ((lane >> 4) * 16)) ^ ((r & 7) << 4);
        bg[fj] = *reinterpret_cast<const bf16x8*>(lB + byte);
      }
#pragma unroll
      for (int fi = 0; fi < 4; ++fi)
#pragma unroll
        for (int fj = 0; fj < 4; ++fj)
          acc[fi][fj] =
              __builtin_amdgcn_mfma_f32_16x16x32_bf16(af[fi], bg[fj], acc[fi][fj], 0, 0, 0);
    }
  }
#pragma unroll
  for (int fi = 0; fi < 4; ++fi) {
#pragma unroll
    for (int fj = 0; fj < 4; ++fj) {
      int n = bn * 128 + wc + fj * 16 + (lane & 15);
      float bv = bias[n];
#pragma unroll
      for (int r = 0; r < 4; ++r) {
        size_t m = bm * 128 + wr + fi * 16 + ((lane >> 4) * 4) + r;
        float val = acc[fi][fj][r] + bv;
        if constexpr (sizeof(TOUT) == 2)
          reinterpret_cast<ushort*>(Cg)[m * 1024 + n] = f2bf(val);
        else
          reinterpret_cast<float*>(Cg)[m * 1024 + n] = val;
      }
    }
  }
}

// ---------------- attention: one block per (b,s'), head-axis softmax ------
__global__ __launch_bounds__(512) void attn_kernel(const ushort* __restrict__ Q,
                                                   const ushort* __restrict__ Kl,
                                                   const ushort* __restrict__ Vl,
                                                   ushort* __restrict__ Aout) {
  const int bs = blockIdx.x;
  const int b = bs >> 11, sp = bs & 2047;
  const int tid = threadIdx.x;
  const int wave = tid >> 6, lane = tid & 63;

  __shared__ ushort qrow[1024];
  __shared__ float sc[16][32];
  __shared__ float attnw[16][32];
  __shared__ float mx[32], rinv[32];

  reinterpret_cast<uint*>(qrow)[tid] =
      reinterpret_cast<const uint*>(Q + (size_t)bs * 1024)[tid];
  __syncthreads();

  const int wp = lane & 31, half = lane >> 5;
#pragma unroll
  for (int hh = 0; hh < 2; ++hh) {
    const int h = wave * 2 + hh;
    const int s_k = h * 128 + (sp >> 4);
    const int w_k = (sp & 15) * 2 + (wp >> 4);
    const ushort* kp =
        Kl + (((size_t)(b * 2048 + s_k) * 32) + w_k) * 1024 + (wp & 15) * 64 + half * 32;
    const ushort* qp = qrow + h * 64 + half * 32;
    float dot = 0.f;
#pragma unroll
    for (int j = 0; j < 32; j += 8) {
      int4 kv = *reinterpret_cast<const int4*>(kp + j);
      int4 qv = *reinterpret_cast<const int4*>(qp + j);
      const ushort* ka = reinterpret_cast<const ushort*>(&kv);
      const ushort* qa = reinterpret_cast<const ushort*>(&qv);
#pragma unroll
      for (int t = 0; t < 8; ++t) dot += bf2f(ka[t]) * bf2f(qa[t]);
    }
    dot += __shfl_xor(dot, 32);
    if (half == 0) sc[h][wp] = dot * 0.125f;
  }
  __syncthreads();
  if (tid < 32) {
    float m = sc[0][tid];
#pragma unroll
    for (int h = 1; h < 16; ++h) m = fmaxf(m, sc[h][tid]);
    float s = 0.f;
#pragma unroll
    for (int h = 0; h < 16; ++h) s += __expf(sc[h][tid] - m);
    mx[tid] = m;
    rinv[tid] = 1.f / s;
  }
  __syncthreads();
  if (lane < 32) {
#pragma unroll
    for (int hh = 0; hh < 2; ++hh) {
      const int h = wave * 2 + hh;
      attnw[h][lane] = __expf(sc[h][lane] - mx[lane]) * rinv[lane];
    }
  }
  __syncthreads();
#pragma unroll
  for (int hh = 0; hh < 2; ++hh) {
    const int h = wave * 2 + hh;
    const int s_k = h * 128 + (sp >> 4);
    const size_t vb = (((size_t)(b * 2048 + s_k) * 32) + (sp & 15) * 2) * 1024;
    float a = 0.f;
#pragma unroll
    for (int w2 = 0; w2 < 32; ++w2) {
      float wgt = attnw[h][w2];
      a += wgt * bf2f(Vl[vb + (size_t)(w2 >> 4) * 1024 + (w2 & 15) * 64 + lane]);
    }
    Aout[(((size_t)(b * 16 + h)) * 2048 + sp) * 64 + lane] = f2bf(a);
  }
}

extern "C" void kernel_launch(void* const* d_in, const int* in_sizes, int n_in,
                              void* d_out, int out_size, void* d_ws, size_t ws_size,
                              hipStream_t stream) {
  const float* q = (const float*)d_in[0];
  const float* k = (const float*)d_in[1];
  const float* v = (const float*)d_in[2];
  const float* Wq = (const float*)d_in[3];
  const float* bq = (const float*)d_in[4];
  const float* Wk = (const float*)d_in[5];
  const float* bk = (const float*)d_in[6];
  const float* Wv = (const float*)d_in[7];
  const float* bv = (const float*)d_in[8];
  const float* Wo = (const float*)d_in[9];
  const float* bo = (const float*)d_in[10];
  float* out = (float*)d_out;

  char* ws = (char*)d_ws;
  const size_t MB = 1u << 20;
  ushort* Qlin = (ushort*)ws;                    // 8 MiB
  ushort* Aws  = (ushort*)(ws + 8 * MB);         // 8 MiB
  ushort* wkbf = (ushort*)(ws + 16 * MB);        // 2 MiB
  ushort* wvbf = (ushort*)(ws + 18 * MB);        // 2 MiB
  ushort* wqbf = (ushort*)(ws + 20 * MB);        // 2 MiB
  ushort* wobf = (ushort*)(ws + 22 * MB);        // 2 MiB
  ushort* qbf  = (ushort*)(ws + 24 * MB);        // 8 MiB
  ushort* Klin = (ushort*)(ws + 32 * MB);        // 256 MiB
  ushort* Vlin = (ushort*)(ws + 288 * MB);       // 256 MiB
  const bool full = ws_size >= 800 * MB;

  if (full) {
    cast_kernel<<<dim3(512), 256, 0, stream>>>(Wq, wqbf, 1048576L);
    cast_kernel<<<dim3(512), 256, 0, stream>>>(Wk, wkbf, 1048576L);
    cast_kernel<<<dim3(512), 256, 0, stream>>>(Wv, wvbf, 1048576L);
    cast_kernel<<<dim3(512), 256, 0, stream>>>(Wo, wobf, 1048576L);
    cast_kernel<<<dim3(2048), 256, 0, stream>>>(q, qbf, 4194304L);
    gemm_lds<ushort><<<dim3(256), 256, 0, stream>>>(qbf, wqbf, bq, Qlin);
    gemm_big<<<dim3(2048), 512, 0, stream>>>(k, wkbf, bk, Klin);
    gemm_big<<<dim3(2048), 512, 0, stream>>>(v, wvbf, bv, Vlin);
    attn_kernel<<<dim3(4096), dim3(512), 0, stream>>>(Qlin, Klin, Vlin, Aws);
    gemm_lds<float><<<dim3(256), 256, 0, stream>>>(Aws, wobf, bo, out);
  } else {
    gemm_bias<float, ushort><<<dim3(8, 32), 256, 0, stream>>>(q, Wq, bq, Qlin);
    gemm_bias<float, ushort><<<dim3(8, 1024), 256, 0, stream>>>(k, Wk, bk, Klin);
    gemm_bias<float, ushort><<<dim3(8, 1024), 256, 0, stream>>>(v, Wv, bv, Vlin);
    attn_kernel<<<dim3(4096), dim3(512), 0, stream>>>(Qlin, Klin, Vlin, Aws);
    gemm_bias<ushort, float><<<dim3(8, 32), 256, 0, stream>>>(Aws, Wo, bo, out);
  }
}

// Round 5
// 969.847 us; speedup vs baseline: 2.3441x; 2.3402x over previous
//
#include <hip/hip_runtime.h>
#include <hip/hip_bf16.h>

// B=2, S=2048, W=32, D=1024, H=16, hd=64
// Pipeline (full path):
//   bf16-cast: Wq,Wk,Wv,Wo,q (small only)
//   K/V GEMM: gemm_big = 256x256 tile, BK=64, 8-phase kk-split schedule with
//             FUSED fp32->bf16 A-cast, register-budgeted to ~225 VGPR:
//             - phases split by (kk, fj-pair): live frags = A8[8]+Bf[2] (40)
//               instead of 96 (round-3/4 demand ~310 -> 1.3GB scratch spills).
//             - A staged via 8x global_load_dwordx4 (sa: ph2->CVT ph4,
//               sb: ph6->CVT ph8; disjoint live ranges share 32 regs).
//             - CVT writes buf.A only after its last read's trailing barrier
//               (ph3/ph7); B via global_load_lds, drains vmcnt(0) at ph4/ph8
//               ends (all in-flight loads >=2 phases old -> free).
//             - amdgpu_waves_per_eu(2,2): explicit 256-VGPR budget (LDS
//               128KiB caps at 1 block/CU = 2 waves/EU anyway).
//   Q/O GEMM: gemm_lds (128x128)
//   attn: per (b,s') head-softmax gather-attention -> A (4096x1024 bf16)
//   out  = A@Wo^T+bo (fp32)

#define DEVI __device__ __forceinline__

typedef __attribute__((ext_vector_type(8))) short bf16x8;
typedef __attribute__((ext_vector_type(4))) float f32x4;
typedef const __attribute__((address_space(1))) void* gvp;
typedef __attribute__((address_space(3))) void* lvp;

DEVI ushort f2bf(float f) {
  uint u = __float_as_uint(f);
  u = u + 0x7fffu + ((u >> 16) & 1u);
  return (ushort)(u >> 16);
}
DEVI float bf2f(ushort u) { return __uint_as_float(((uint)u) << 16); }

// ---------------- elementwise fp32 -> bf16 cast (RNE), 8 elems/thread ----
__global__ __launch_bounds__(256) void cast_kernel(const float* __restrict__ in,
                                                   ushort* __restrict__ out,
                                                   long n) {
  long i = ((long)blockIdx.x * 256 + threadIdx.x) * 8;
  const long stride = (long)gridDim.x * 256 * 8;
  for (; i < n; i += stride) {
    float4 a = *reinterpret_cast<const float4*>(in + i);
    float4 b = *reinterpret_cast<const float4*>(in + i + 4);
    ushort o[8];
    o[0] = f2bf(a.x); o[1] = f2bf(a.y); o[2] = f2bf(a.z); o[3] = f2bf(a.w);
    o[4] = f2bf(b.x); o[5] = f2bf(b.y); o[6] = f2bf(b.z); o[7] = f2bf(b.w);
    *reinterpret_cast<int4*>(out + i) = *reinterpret_cast<const int4*>(o);
  }
}

// ---------------- fused-cast kk-split 8-phase GEMM ------------------------
// C = A(fp32) @ W(bf16)^T + bias, bf16 out. Tile 256x256, BK=64, 16 K-tiles,
// 8 iters x 2 tiles. LDS: buf0 { A 32K (A0@0,A1@16K), B 32K (B0@32K,B1@48K) },
// buf1 = +64K. Row = 128B = 8 chunks of 16B; stored chunk p of row r holds
// source chunk p^(r&7); fragment read swz ((kk*4+q)^(lm&7))*16.
// Steady iter (j=2it; buf0=tile j, buf1=tile j+1):
//  ph1 (kk0,fj01,buf0): LDA8 swz0 + LDB2           STG B0(j+1)->buf1
//  ph2 (kk0,fj23):      LDB2 + AISS sa<-A(j+2)     STG B1(j+1)->buf1
//  ph3 (kk1,fj01):      LDA8 swz1 + LDB2           [trailing bar gates ph4 CVT]
//  ph4 (kk1,fj23):      LDB2 + CVT sa->buf0.A(j+2); end: vmcnt(0)+bar
//  ph5..ph8: mirror on buf1 (STG B(j+2)->buf0, sb<-A(j+3), CVT->buf1.A(j+3));
//            end: vmcnt(0)+bar.
// Tail it7: skip AISS/CVT/ph5-6 STG; keep ph4 drain (buf1.B residency).
template <int FJ0>
DEVI void mfma16b(f32x4 (&acc)[8][4], const bf16x8 (&A)[8], const bf16x8 (&B)[2]) {
  __builtin_amdgcn_s_setprio(1);
#pragma unroll
  for (int fi = 0; fi < 8; ++fi)
#pragma unroll
    for (int j = 0; j < 2; ++j)
      acc[fi][FJ0 + j] = __builtin_amdgcn_mfma_f32_16x16x32_bf16(
          A[fi], B[j], acc[fi][FJ0 + j], 0, 0, 0);
  __builtin_amdgcn_s_setprio(0);
}

__global__ __launch_bounds__(512)
__attribute__((amdgpu_waves_per_eu(2, 2)))
void gemm_big(const float* __restrict__ Ag, const ushort* __restrict__ Wg,
              const float* __restrict__ bias, ushort* __restrict__ Cg) {
  constexpr int K = 1024;
  __shared__ char lds[131072];
  const int tid = threadIdx.x;
  const int lane = tid & 63;
  const int wave = tid >> 6;
  const int wm = wave >> 2;
  const int wn = wave & 3;
  const int d = blockIdx.x;
  const int bn = (d >> 3) & 3;
  const size_t bm = (size_t)(d & 7) * (gridDim.x >> 5) + (d >> 5);

  const ushort* bB = Wg + (size_t)bn * 256 * K;

  // staging: chunk f=tid -> row r0=tid>>3, source chunk c0=(tid&7)^(r0&7)
  // (same c0 for rows r0+64k). A fp32 chunk = 8 floats = 2 float4.
  const int r0 = tid >> 3;
  const int c0 = (tid & 7) ^ (r0 & 7);
  const float* pR0 = Ag + bm * 256 * K + (size_t)r0 * K + c0 * 8;
  const float* pR1 = pR0 + 64 * K;
  const ushort* bS0 = bB + (size_t)r0 * K + c0 * 8;
  const ushort* bS1 = bB + (size_t)(r0 + 64) * K + c0 * 8;
  const ushort* bS2 = bB + (size_t)(r0 + 128) * K + c0 * 8;
  const ushort* bS3 = bB + (size_t)(r0 + 192) * K + c0 * 8;

  // fragment-read offsets
  const int lm = lane & 15;
  const int q = lane >> 4;
  const int rowB = lm * 128;
  const int swz0 = (q ^ (lm & 7)) * 16;
  const int swz1 = ((4 + q) ^ (lm & 7)) * 16;
  const char* ldsc = (const char*)lds;
  const char* p0A = ldsc + wm * 16384 + rowB;
  const char* p0B = ldsc + 32768 + (wn >> 1) * 16384 + (wn & 1) * 8192 + rowB;
  const char* p1A = p0A + 65536;
  const char* p1B = p0B + 65536;

  f32x4 acc[8][4] = {};
  bf16x8 A8[8];
  bf16x8 Bf[2];
  float4 sa[8], sb[8];

#define SB0 __builtin_amdgcn_sched_barrier(0)
#define BAR __builtin_amdgcn_s_barrier()
#define STG(p0, p1, ktE, ldsOff)                                                 \
  {                                                                              \
    __builtin_amdgcn_global_load_lds((gvp)((p0) + (ktE)),                        \
                                     (lvp)(lds + (ldsOff) + tid * 16), 16, 0, 0);\
    __builtin_amdgcn_global_load_lds((gvp)((p1) + (ktE)),                        \
                                     (lvp)(lds + (ldsOff) + 8192 + tid * 16),    \
                                     16, 0, 0);                                  \
  }
#define AISS8(set, off)                                                  \
  {                                                                      \
    set[0] = *reinterpret_cast<const float4*>(pR0 + (off));              \
    set[1] = *reinterpret_cast<const float4*>(pR0 + (off) + 4);          \
    set[2] = *reinterpret_cast<const float4*>(pR1 + (off));              \
    set[3] = *reinterpret_cast<const float4*>(pR1 + (off) + 4);          \
    set[4] = *reinterpret_cast<const float4*>(pR0 + 131072 + (off));     \
    set[5] = *reinterpret_cast<const float4*>(pR0 + 131072 + (off) + 4); \
    set[6] = *reinterpret_cast<const float4*>(pR1 + 131072 + (off));     \
    set[7] = *reinterpret_cast<const float4*>(pR1 + 131072 + (off) + 4); \
  }
#define CVTPAIR(v0, v1, dstoff)                                             \
  {                                                                         \
    uint w0, w1, w2, w3;                                                    \
    asm("v_cvt_pk_bf16_f32 %0,%1,%2" : "=v"(w0) : "v"((v0).x), "v"((v0).y)); \
    asm("v_cvt_pk_bf16_f32 %0,%1,%2" : "=v"(w1) : "v"((v0).z), "v"((v0).w)); \
    asm("v_cvt_pk_bf16_f32 %0,%1,%2" : "=v"(w2) : "v"((v1).x), "v"((v1).y)); \
    asm("v_cvt_pk_bf16_f32 %0,%1,%2" : "=v"(w3) : "v"((v1).z), "v"((v1).w)); \
    *reinterpret_cast<uint4*>(lds + (dstoff) + tid * 16) =                  \
        make_uint4(w0, w1, w2, w3);                                         \
  }
#define CVT8(set, base)                 \
  {                                     \
    CVTPAIR(set[0], set[1], (base));    \
    CVTPAIR(set[2], set[3], (base) + 8192);  \
    CVTPAIR(set[4], set[5], (base) + 16384); \
    CVTPAIR(set[6], set[7], (base) + 24576); \
  }
#define PH_SYNC()                                    \
  __builtin_amdgcn_s_barrier();                      \
  asm volatile("s_waitcnt lgkmcnt(0)" ::: "memory"); \
  SB0;
#define LDA8(p, swz)                                                       \
  _Pragma("unroll") for (int i_ = 0; i_ < 8; ++i_) {                       \
    A8[i_] = *reinterpret_cast<const bf16x8*>((p) + i_ * 2048 + (swz));    \
  }
#define LDB2(p, fjb, swz)                                                  \
  {                                                                        \
    Bf[0] = *reinterpret_cast<const bf16x8*>((p) + (fjb) + (swz));         \
    Bf[1] = *reinterpret_cast<const bf16x8*>((p) + (fjb) + 2048 + (swz));  \
  }

  // ---- prologue: buf0 <- tile0 (A cvt + B stg); buf1.A <- tile1 (cvt) ----
  STG(bS0, bS1, 0, 32768); SB0;
  STG(bS2, bS3, 0, 49152); SB0;
  AISS8(sa, 0); SB0;
  AISS8(sb, 64); SB0;
  CVT8(sa, 0);
  CVT8(sb, 65536);
  asm volatile("s_waitcnt vmcnt(0)" ::: "memory");
  asm volatile("s_waitcnt lgkmcnt(0)" ::: "memory");
  BAR;
  SB0;

#define ITER(M)                                                           \
  {                                                                       \
    const int ktB1 = (2 * it + 1) * 64;                                   \
    const int ktB2 = (2 * it + 2) * 64;                                   \
    const int ktA2 = (2 * it + 2) * 64;                                   \
    const int ktA3 = (2 * it + 3) * 64;                                   \
    /* ph1: buf0 kk0 fj01 */                                              \
    LDA8(p0A, swz0); LDB2(p0B, 0, swz0);                                  \
    STG(bS0, bS1, ktB1, 98304);                                           \
    PH_SYNC(); mfma16b<0>(acc, A8, Bf); BAR;                              \
    /* ph2: buf0 kk0 fj23; issue sa <- A(j+2) */                          \
    LDB2(p0B, 4096, swz0);                                                \
    if (M == 0) { AISS8(sa, ktA2); }                                      \
    STG(bS2, bS3, ktB1, 114688);                                          \
    PH_SYNC(); mfma16b<2>(acc, A8, Bf); BAR;                              \
    /* ph3: buf0 kk1 fj01 (trailing bar gates ph4's CVT) */               \
    LDA8(p0A, swz1); LDB2(p0B, 0, swz1);                                  \
    PH_SYNC(); mfma16b<0>(acc, A8, Bf); BAR;                              \
    /* ph4: buf0 kk1 fj23; CVT sa -> buf0.A(j+2); drain B(j+1) */         \
    LDB2(p0B, 4096, swz1);                                                \
    if (M == 0) { CVT8(sa, 0); }                                          \
    PH_SYNC(); mfma16b<2>(acc, A8, Bf);                                   \
    SB0;                                                                  \
    asm volatile("s_waitcnt vmcnt(0)" ::: "memory");                      \
    BAR; SB0;                                                             \
    /* ph5: buf1 kk0 fj01 */                                              \
    LDA8(p1A, swz0); LDB2(p1B, 0, swz0);                                  \
    if (M == 0) STG(bS0, bS1, ktB2, 32768);                               \
    PH_SYNC(); mfma16b<0>(acc, A8, Bf); BAR;                              \
    /* ph6: buf1 kk0 fj23; issue sb <- A(j+3) */                          \
    LDB2(p1B, 4096, swz0);                                                \
    if (M == 0) { AISS8(sb, ktA3); STG(bS2, bS3, ktB2, 49152); }          \
    PH_SYNC(); mfma16b<2>(acc, A8, Bf); BAR;                              \
    /* ph7: buf1 kk1 fj01 (trailing bar gates ph8's CVT) */               \
    LDA8(p1A, swz1); LDB2(p1B, 0, swz1);                                  \
    PH_SYNC(); mfma16b<0>(acc, A8, Bf); BAR;                              \
    /* ph8: buf1 kk1 fj23; CVT sb -> buf1.A(j+3); drain B(j+2) */         \
    LDB2(p1B, 4096, swz1);                                                \
    if (M == 0) { CVT8(sb, 65536); }                                      \
    PH_SYNC(); mfma16b<2>(acc, A8, Bf);                                   \
    if (M == 0) {                                                         \
      SB0;                                                                \
      asm volatile("s_waitcnt vmcnt(0)" ::: "memory");                    \
      BAR; SB0;                                                           \
    }                                                                     \
  }

#pragma unroll 1
  for (int it = 0; it < 7; ++it) ITER(0);
  { const int it = 7; ITER(1); }
#undef ITER
#undef STG
#undef AISS8
#undef CVTPAIR
#undef CVT8
#undef PH_SYNC
#undef LDA8
#undef LDB2
#undef SB0
#undef BAR

  // ---- epilogue: C/D layout col=lane&15, row=(lane>>4)*4+r ----
#pragma unroll
  for (int fi = 0; fi < 8; ++fi) {
#pragma unroll
    for (int fj = 0; fj < 4; ++fj) {
      int n = bn * 256 + wn * 64 + fj * 16 + lm;
      float bv = bias[n];
#pragma unroll
      for (int r = 0; r < 4; ++r) {
        size_t m = bm * 256 + wm * 128 + fi * 16 + ((lane >> 4) * 4) + r;
        Cg[m * 1024 + n] = f2bf(acc[fi][fj][r] + bv);
      }
    }
  }
}

// ---------------- 128x128 gload_lds GEMM (Q/O; verified) -------------------
template <typename TOUT>
__global__ __launch_bounds__(256) void gemm_lds(const ushort* __restrict__ Ag,
                                                const ushort* __restrict__ Wg,
                                                const float* __restrict__ bias,
                                                TOUT* __restrict__ Cg) {
  constexpr int K = 1024;
  __shared__ ushort lA[128 * 64];
  __shared__ ushort lB[128 * 64];
  const int tid = threadIdx.x;
  const int lane = tid & 63;
  const int wave = tid >> 6;
  const int wr = (wave >> 1) * 64;
  const int wc = (wave & 1) * 64;
  const int d = blockIdx.x;
  const int bn = (d >> 3) & 7;
  const size_t bm = (size_t)(d & 7) * (gridDim.x >> 6) + (d >> 6);

  const ushort* aB = Ag + bm * 128 * K;
  const ushort* bB = Wg + (size_t)bn * 128 * K;
  const int srow = wave * 32 + (lane >> 3);
  const int scol = ((lane & 7) ^ (lane >> 3)) * 8;
  char* lAc = (char*)lA;
  char* lBc = (char*)lB;

  f32x4 acc[4][4] = {};

  for (int kt = 0; kt < K; kt += 64) {
    __syncthreads();
#pragma unroll
    for (int c = 0; c < 4; ++c) {
      __builtin_amdgcn_global_load_lds(
          (gvp)(aB + (size_t)(srow + c * 8) * K + kt + scol),
          (lvp)(lAc + wave * 4096 + c * 1024), 16, 0, 0);
      __builtin_amdgcn_global_load_lds(
          (gvp)(bB + (size_t)(srow + c * 8) * K + kt + scol),
          (lvp)(lBc + wave * 4096 + c * 1024), 16, 0, 0);
    }
    __syncthreads();
#pragma unroll
    for (int kk = 0; kk < 2; ++kk) {
      bf16x8 af[4], bg[4];
#pragma unroll
      for (int fi = 0; fi < 4; ++fi) {
        int r = wr + fi * 16 + (lane & 15);
        int byte = (r * 128 + kk * 64 + ((lane >> 4) * 16)) ^ ((r & 7) << 4);
        af[fi] = *reinterpret_cast<const bf16x8*>(lAc + byte);
      }
#pragma unroll
      for (int fj = 0; fj < 4; ++fj) {
        int r = wc + fj * 16 + (lane & 15);
        int byte = (r * 128 + kk * 64 + ((lane >> 4) * 16)) ^ ((r & 7) << 4);
        bg[fj] = *reinterpret_cast<const bf16x8*>(lBc + byte);
      }
#pragma unroll
      for (int fi = 0; fi < 4; ++fi)
#pragma unroll
        for (int fj = 0; fj < 4; ++fj)
          acc[fi][fj] = __builtin_amdgcn_mfma_f32_16x16x32_bf16(af[fi], bg[fj],
                                                                acc[fi][fj], 0, 0, 0);
    }
  }
#pragma unroll
  for (int fi = 0; fi < 4; ++fi) {
#pragma unroll
    for (int fj = 0; fj < 4; ++fj) {
      int n = bn * 128 + wc + fj * 16 + (lane & 15);
      float bv = bias[n];
#pragma unroll
      for (int r = 0; r < 4; ++r) {
        size_t m = bm * 128 + wr + fi * 16 + ((lane >> 4) * 4) + r;
        float val = acc[fi][fj][r] + bv;
        if constexpr (sizeof(TOUT) == 2)
          reinterpret_cast<ushort*>(Cg)[m * 1024 + n] = f2bf(val);
        else
          reinterpret_cast<float*>(Cg)[m * 1024 + n] = val;
      }
    }
  }
}

// ------------- reg-staged GEMM (fp32 A): fallback path only ---------------
template <typename TIN, typename TOUT>
__global__ __launch_bounds__(256) void gemm_bias(const TIN* __restrict__ Ag,
                                                 const float* __restrict__ Wg,
                                                 const float* __restrict__ bias,
                                                 TOUT* __restrict__ Cg) {
  constexpr int K = 1024;
  __shared__ char lA[128 * 64 * 2];
  __shared__ char lB[128 * 64 * 2];
  const int tid = threadIdx.x;
  const int lane = tid & 63;
  const int wave = tid >> 6;
  const int wr = (wave >> 1) * 64;
  const int wc = (wave & 1) * 64;
  const int bn = blockIdx.x;
  const size_t bm = blockIdx.y;

  const TIN* aBase = Ag + bm * 128 * K;
  const float* bBase = Wg + (size_t)bn * 128 * K;

  f32x4 acc[4][4] = {};

  for (int kt = 0; kt < K; kt += 64) {
    __syncthreads();
    if constexpr (sizeof(TIN) == 4) {
#pragma unroll
      for (int i = 0; i < 8; ++i) {
        int f = tid + i * 256;
        int row = f >> 4, c4 = f & 15;
        const float4 v = *reinterpret_cast<const float4*>(
            reinterpret_cast<const float*>(aBase) + (size_t)row * K + kt + c4 * 4);
        ushort4 pk;
        pk.x = f2bf(v.x); pk.y = f2bf(v.y); pk.z = f2bf(v.z); pk.w = f2bf(v.w);
        int byte = (row * 128 + c4 * 8) ^ ((row & 7) << 4);
        *reinterpret_cast<ushort4*>(lA + byte) = pk;
      }
    } else {
#pragma unroll
      for (int i = 0; i < 4; ++i) {
        int f = tid + i * 256;
        int row = f >> 3, c8 = f & 7;
        int4 v = *reinterpret_cast<const int4*>(
            reinterpret_cast<const ushort*>(aBase) + (size_t)row * K + kt + c8 * 8);
        int byte = (row * 128 + c8 * 16) ^ ((row & 7) << 4);
        *reinterpret_cast<int4*>(lA + byte) = v;
      }
    }
#pragma unroll
    for (int i = 0; i < 8; ++i) {
      int f = tid + i * 256;
      int row = f >> 4, c4 = f & 15;
      const float4 v =
          *reinterpret_cast<const float4*>(bBase + (size_t)row * K + kt + c4 * 4);
      ushort4 pk;
      pk.x = f2bf(v.x); pk.y = f2bf(v.y); pk.z = f2bf(v.z); pk.w = f2bf(v.w);
      int byte = (row * 128 + c4 * 8) ^ ((row & 7) << 4);
      *reinterpret_cast<ushort4*>(lB + byte) = pk;
    }
    __syncthreads();
#pragma unroll
    for (int kk = 0; kk < 2; ++kk) {
      bf16x8 af[4], bg[4];
#pragma unroll
      for (int fi = 0; fi < 4; ++fi) {
        int r = wr + fi * 16 + (lane & 15);
        int byte = (r * 128 + kk * 64 + ((lane >> 4) * 16)) ^ ((r & 7) << 4);
        af[fi] = *reinterpret_cast<const bf16x8*>(lA + byte);
      }
#pragma unroll
      for (int fj = 0; fj < 4; ++fj) {
        int r = wc + fj * 16 + (lane & 15);
        int byte = (r * 128 + kk * 64 + ((lane >> 4) * 16)) ^ ((r & 7) << 4);
        bg[fj] = *reinterpret_cast<const bf16x8*>(lB + byte);
      }
#pragma unroll
      for (int fi = 0; fi < 4; ++fi)
#pragma unroll
        for (int fj = 0; fj < 4; ++fj)
          acc[fi][fj] =
              __builtin_amdgcn_mfma_f32_16x16x32_bf16(af[fi], bg[fj], acc[fi][fj], 0, 0, 0);
    }
  }
#pragma unroll
  for (int fi = 0; fi < 4; ++fi) {
#pragma unroll
    for (int fj = 0; fj < 4; ++fj) {
      int n = bn * 128 + wc + fj * 16 + (lane & 15);
      float bv = bias[n];
#pragma unroll
      for (int r = 0; r < 4; ++r) {
        size_t m = bm * 128 + wr + fi * 16 + ((lane >> 4) * 4) + r;
        float val = acc[fi][fj][r] + bv;
        if constexpr (sizeof(TOUT) == 2)
          reinterpret_cast<ushort*>(Cg)[m * 1024 + n] = f2bf(val);
        else
          reinterpret_cast<float*>(Cg)[m * 1024 + n] = val;
      }
    }
  }
}

// ---------------- attention: one block per (b,s'), head-axis softmax ------
__global__ __launch_bounds__(512) void attn_kernel(const ushort* __restrict__ Q,
                                                   const ushort* __restrict__ Kl,
                                                   const ushort* __restrict__ Vl,
                                                   ushort* __restrict__ Aout) {
  const int bs = blockIdx.x;
  const int b = bs >> 11, sp = bs & 2047;
  const int tid = threadIdx.x;
  const int wave = tid >> 6, lane = tid & 63;

  __shared__ ushort qrow[1024];
  __shared__ float sc[16][32];
  __shared__ float attnw[16][32];
  __shared__ float mx[32], rinv[32];

  reinterpret_cast<uint*>(qrow)[tid] =
      reinterpret_cast<const uint*>(Q + (size_t)bs * 1024)[tid];
  __syncthreads();

  const int wp = lane & 31, half = lane >> 5;
#pragma unroll
  for (int hh = 0; hh < 2; ++hh) {
    const int h = wave * 2 + hh;
    const int s_k = h * 128 + (sp >> 4);
    const int w_k = (sp & 15) * 2 + (wp >> 4);
    const ushort* kp =
        Kl + (((size_t)(b * 2048 + s_k) * 32) + w_k) * 1024 + (wp & 15) * 64 + half * 32;
    const ushort* qp = qrow + h * 64 + half * 32;
    float dot = 0.f;
#pragma unroll
    for (int j = 0; j < 32; j += 8) {
      int4 kv = *reinterpret_cast<const int4*>(kp + j);
      int4 qv = *reinterpret_cast<const int4*>(qp + j);
      const ushort* ka = reinterpret_cast<const ushort*>(&kv);
      const ushort* qa = reinterpret_cast<const ushort*>(&qv);
#pragma unroll
      for (int t = 0; t < 8; ++t) dot += bf2f(ka[t]) * bf2f(qa[t]);
    }
    dot += __shfl_xor(dot, 32);
    if (half == 0) sc[h][wp] = dot * 0.125f;
  }
  __syncthreads();
  if (tid < 32) {
    float m = sc[0][tid];
#pragma unroll
    for (int h = 1; h < 16; ++h) m = fmaxf(m, sc[h][tid]);
    float s = 0.f;
#pragma unroll
    for (int h = 0; h < 16; ++h) s += __expf(sc[h][tid] - m);
    mx[tid] = m;
    rinv[tid] = 1.f / s;
  }
  __syncthreads();
  if (lane < 32) {
#pragma unroll
    for (int hh = 0; hh < 2; ++hh) {
      const int h = wave * 2 + hh;
      attnw[h][lane] = __expf(sc[h][lane] - mx[lane]) * rinv[lane];
    }
  }
  __syncthreads();
#pragma unroll
  for (int hh = 0; hh < 2; ++hh) {
    const int h = wave * 2 + hh;
    const int s_k = h * 128 + (sp >> 4);
    const size_t vb = (((size_t)(b * 2048 + s_k) * 32) + (sp & 15) * 2) * 1024;
    float a = 0.f;
#pragma unroll
    for (int w2 = 0; w2 < 32; ++w2) {
      float wgt = attnw[h][w2];
      a += wgt * bf2f(Vl[vb + (size_t)(w2 >> 4) * 1024 + (w2 & 15) * 64 + lane]);
    }
    Aout[(((size_t)(b * 16 + h)) * 2048 + sp) * 64 + lane] = f2bf(a);
  }
}

extern "C" void kernel_launch(void* const* d_in, const int* in_sizes, int n_in,
                              void* d_out, int out_size, void* d_ws, size_t ws_size,
                              hipStream_t stream) {
  const float* q = (const float*)d_in[0];
  const float* k = (const float*)d_in[1];
  const float* v = (const float*)d_in[2];
  const float* Wq = (const float*)d_in[3];
  const float* bq = (const float*)d_in[4];
  const float* Wk = (const float*)d_in[5];
  const float* bk = (const float*)d_in[6];
  const float* Wv = (const float*)d_in[7];
  const float* bv = (const float*)d_in[8];
  const float* Wo = (const float*)d_in[9];
  const float* bo = (const float*)d_in[10];
  float* out = (float*)d_out;

  char* ws = (char*)d_ws;
  const size_t MB = 1u << 20;
  ushort* Qlin = (ushort*)ws;                    // 8 MiB
  ushort* Aws  = (ushort*)(ws + 8 * MB);         // 8 MiB
  ushort* wkbf = (ushort*)(ws + 16 * MB);        // 2 MiB
  ushort* wvbf = (ushort*)(ws + 18 * MB);        // 2 MiB
  ushort* wqbf = (ushort*)(ws + 20 * MB);        // 2 MiB
  ushort* wobf = (ushort*)(ws + 22 * MB);        // 2 MiB
  ushort* qbf  = (ushort*)(ws + 24 * MB);        // 8 MiB
  ushort* Klin = (ushort*)(ws + 32 * MB);        // 256 MiB
  ushort* Vlin = (ushort*)(ws + 288 * MB);       // 256 MiB
  const bool full = ws_size >= 800 * MB;

  if (full) {
    cast_kernel<<<dim3(512), 256, 0, stream>>>(Wq, wqbf, 1048576L);
    cast_kernel<<<dim3(512), 256, 0, stream>>>(Wk, wkbf, 1048576L);
    cast_kernel<<<dim3(512), 256, 0, stream>>>(Wv, wvbf, 1048576L);
    cast_kernel<<<dim3(512), 256, 0, stream>>>(Wo, wobf, 1048576L);
    cast_kernel<<<dim3(2048), 256, 0, stream>>>(q, qbf, 4194304L);
    gemm_lds<ushort><<<dim3(256), 256, 0, stream>>>(qbf, wqbf, bq, Qlin);
    gemm_big<<<dim3(2048), 512, 0, stream>>>(k, wkbf, bk, Klin);
    gemm_big<<<dim3(2048), 512, 0, stream>>>(v, wvbf, bv, Vlin);
    attn_kernel<<<dim3(4096), dim3(512), 0, stream>>>(Qlin, Klin, Vlin, Aws);
    gemm_lds<float><<<dim3(256), 256, 0, stream>>>(Aws, wobf, bo, out);
  } else {
    gemm_bias<float, ushort><<<dim3(8, 32), 256, 0, stream>>>(q, Wq, bq, Qlin);
    gemm_bias<float, ushort><<<dim3(8, 1024), 256, 0, stream>>>(k, Wk, bk, Klin);
    gemm_bias<float, ushort><<<dim3(8, 1024), 256, 0, stream>>>(v, Wv, bv, Vlin);
    attn_kernel<<<dim3(4096), dim3(512), 0, stream>>>(Qlin, Klin, Vlin, Aws);
    gemm_bias<ushort, float><<<dim3(8, 32), 256, 0, stream>>>(Aws, Wo, bo, out);
  }
}

// Round 6
// 913.660 us; speedup vs baseline: 2.4882x; 1.0615x over previous
//
#include <hip/hip_runtime.h>
#include <hip/hip_bf16.h>

// B=2, S=2048, W=32, D=1024, H=16, hd=64
// Pipeline (full path):
//   bf16-cast: Wq,Wk,Wv,Wo,q (small only)
//   K/V GEMM: gemm_big = 256x256 tile, BK=64, 8-phase kk-split schedule with
//             FUSED fp32->bf16 A-cast. Round-6 schedule: counted vmcnt only
//             (never drain young loads):
//             - ph1 stages BOTH B halves of tile j+1 -> ph4-end wait is
//               vmcnt(8), loads 3 phases old. Mirror ph5 / ph8-end.
//             - ONE shared staging array st[8] (32 VGPR, explicit reuse):
//               AISS ph2 -> CVT ph6 (buf0.A(j+2), 4-phase distance,
//               auto vmcnt(4)); AISS ph6 -> CVT next-iter ph2 (buf1.A(j+1),
//               just-in-time: region free since prev-ph7 + barriers).
//             - Register budget proven in round 5: acc in AGPR (128),
//               arch VGPR <= 128, no spills (WRITE_SIZE == C exactly).
//   Q/O GEMM: gemm_lds (128x128)
//   attn: per (b,s') head-softmax gather-attention -> A (4096x1024 bf16)
//   out  = A@Wo^T+bo (fp32)

#define DEVI __device__ __forceinline__

typedef __attribute__((ext_vector_type(8))) short bf16x8;
typedef __attribute__((ext_vector_type(4))) float f32x4;
typedef const __attribute__((address_space(1))) void* gvp;
typedef __attribute__((address_space(3))) void* lvp;

DEVI ushort f2bf(float f) {
  uint u = __float_as_uint(f);
  u = u + 0x7fffu + ((u >> 16) & 1u);
  return (ushort)(u >> 16);
}
DEVI float bf2f(ushort u) { return __uint_as_float(((uint)u) << 16); }

// ---------------- elementwise fp32 -> bf16 cast (RNE), 8 elems/thread ----
__global__ __launch_bounds__(256) void cast_kernel(const float* __restrict__ in,
                                                   ushort* __restrict__ out,
                                                   long n) {
  long i = ((long)blockIdx.x * 256 + threadIdx.x) * 8;
  const long stride = (long)gridDim.x * 256 * 8;
  for (; i < n; i += stride) {
    float4 a = *reinterpret_cast<const float4*>(in + i);
    float4 b = *reinterpret_cast<const float4*>(in + i + 4);
    ushort o[8];
    o[0] = f2bf(a.x); o[1] = f2bf(a.y); o[2] = f2bf(a.z); o[3] = f2bf(a.w);
    o[4] = f2bf(b.x); o[5] = f2bf(b.y); o[6] = f2bf(b.z); o[7] = f2bf(b.w);
    *reinterpret_cast<int4*>(out + i) = *reinterpret_cast<const int4*>(o);
  }
}

// ---------------- fused-cast kk-split 8-phase GEMM ------------------------
// C = A(fp32) @ W(bf16)^T + bias, bf16 out. Tile 256x256, BK=64, 16 K-tiles,
// 8 iters x 2 tiles. LDS: buf0 { A@0 (A0,A1), B@32K (B0,B1) }, buf1 = +64K.
// Row = 128B = 8 chunks of 16B; stored chunk p of row r holds source chunk
// p^(r&7); fragment read swz ((kk*4+q)^(lm&7))*16.
// Steady iter (j=2it; buf0=tile j, buf1=tile j+1):
//  ph1 (buf0 kk0 fj01): LDA8+LDB2   STG B(j+1) BOTH halves -> buf1.B
//  ph2 (buf0 kk0 fj23): LDB2  CVT st -> buf1.A(j+1)  AISS st <- A(j+2)
//  ph3 (buf0 kk1 fj01): LDA8+LDB2
//  ph4 (buf0 kk1 fj23): LDB2;  end: vmcnt(8)+bar  [B(j+1) resident, 3ph old]
//  ph5 (buf1 kk0 fj01): LDA8+LDB2   STG B(j+2) BOTH halves -> buf0.B
//  ph6 (buf1 kk0 fj23): LDB2  CVT st -> buf0.A(j+2)  AISS st <- A(j+3)
//  ph7 (buf1 kk1 fj01): LDA8+LDB2
//  ph8 (buf1 kk1 fj23): LDB2;  end: vmcnt(8)+bar  [B(j+2) resident]
// Waits: manual vmcnt(8) x2 (3-phase-old B); auto vmcnt(4) at CVTs
// (4-phase-old st). Prologue exits with exactly st(A1)x8 in flight.
// Tail it7: ph2 CVT only (no AISS); skip ph5 STG / ph6 CVT+AISS;
// ph4-end vmcnt(0); no final drain needed.
template <int FJ0>
DEVI void mfma16b(f32x4 (&acc)[8][4], const bf16x8 (&A)[8], const bf16x8 (&B)[2]) {
  __builtin_amdgcn_s_setprio(1);
#pragma unroll
  for (int fi = 0; fi < 8; ++fi)
#pragma unroll
    for (int j = 0; j < 2; ++j)
      acc[fi][FJ0 + j] = __builtin_amdgcn_mfma_f32_16x16x32_bf16(
          A[fi], B[j], acc[fi][FJ0 + j], 0, 0, 0);
  __builtin_amdgcn_s_setprio(0);
}

__global__ __launch_bounds__(512)
__attribute__((amdgpu_waves_per_eu(2, 2)))
void gemm_big(const float* __restrict__ Ag, const ushort* __restrict__ Wg,
              const float* __restrict__ bias, ushort* __restrict__ Cg) {
  constexpr int K = 1024;
  __shared__ char lds[131072];
  const int tid = threadIdx.x;
  const int lane = tid & 63;
  const int wave = tid >> 6;
  const int wm = wave >> 2;
  const int wn = wave & 3;
  const int d = blockIdx.x;
  const int bn = (d >> 3) & 3;
  const size_t bm = (size_t)(d & 7) * (gridDim.x >> 5) + (d >> 5);

  const ushort* bB = Wg + (size_t)bn * 256 * K;

  // staging: chunk f=tid -> row r0=tid>>3, source chunk c0=(tid&7)^(r0&7)
  // (same c0 for rows r0+64k). A fp32 chunk = 8 floats = 2 float4.
  const int r0 = tid >> 3;
  const int c0 = (tid & 7) ^ (r0 & 7);
  const float* pR0 = Ag + bm * 256 * K + (size_t)r0 * K + c0 * 8;
  const float* pR1 = pR0 + 64 * K;
  const ushort* bS0 = bB + (size_t)r0 * K + c0 * 8;
  const ushort* bS1 = bB + (size_t)(r0 + 64) * K + c0 * 8;
  const ushort* bS2 = bB + (size_t)(r0 + 128) * K + c0 * 8;
  const ushort* bS3 = bB + (size_t)(r0 + 192) * K + c0 * 8;

  // fragment-read offsets
  const int lm = lane & 15;
  const int q = lane >> 4;
  const int rowB = lm * 128;
  const int swz0 = (q ^ (lm & 7)) * 16;
  const int swz1 = ((4 + q) ^ (lm & 7)) * 16;
  const char* ldsc = (const char*)lds;
  const char* p0A = ldsc + wm * 16384 + rowB;
  const char* p0B = ldsc + 32768 + (wn >> 1) * 16384 + (wn & 1) * 8192 + rowB;
  const char* p1A = p0A + 65536;
  const char* p1B = p0B + 65536;

  f32x4 acc[8][4] = {};
  bf16x8 A8[8];
  bf16x8 Bf[2];
  float4 st[8];  // single shared staging set (explicit live-range reuse)

#define SB0 __builtin_amdgcn_sched_barrier(0)
#define BAR __builtin_amdgcn_s_barrier()
#define STG(p0, p1, ktE, ldsOff)                                                 \
  {                                                                              \
    __builtin_amdgcn_global_load_lds((gvp)((p0) + (ktE)),                        \
                                     (lvp)(lds + (ldsOff) + tid * 16), 16, 0, 0);\
    __builtin_amdgcn_global_load_lds((gvp)((p1) + (ktE)),                        \
                                     (lvp)(lds + (ldsOff) + 8192 + tid * 16),    \
                                     16, 0, 0);                                  \
  }
#define AISS8(off)                                                      \
  {                                                                     \
    st[0] = *reinterpret_cast<const float4*>(pR0 + (off));              \
    st[1] = *reinterpret_cast<const float4*>(pR0 + (off) + 4);          \
    st[2] = *reinterpret_cast<const float4*>(pR1 + (off));              \
    st[3] = *reinterpret_cast<const float4*>(pR1 + (off) + 4);          \
    st[4] = *reinterpret_cast<const float4*>(pR0 + 131072 + (off));     \
    st[5] = *reinterpret_cast<const float4*>(pR0 + 131072 + (off) + 4); \
    st[6] = *reinterpret_cast<const float4*>(pR1 + 131072 + (off));     \
    st[7] = *reinterpret_cast<const float4*>(pR1 + 131072 + (off) + 4); \
  }
#define CVTPAIR(v0, v1, dstoff)                                              \
  {                                                                          \
    uint w0, w1, w2, w3;                                                     \
    asm("v_cvt_pk_bf16_f32 %0,%1,%2" : "=v"(w0) : "v"((v0).x), "v"((v0).y)); \
    asm("v_cvt_pk_bf16_f32 %0,%1,%2" : "=v"(w1) : "v"((v0).z), "v"((v0).w)); \
    asm("v_cvt_pk_bf16_f32 %0,%1,%2" : "=v"(w2) : "v"((v1).x), "v"((v1).y)); \
    asm("v_cvt_pk_bf16_f32 %0,%1,%2" : "=v"(w3) : "v"((v1).z), "v"((v1).w)); \
    *reinterpret_cast<uint4*>(lds + (dstoff) + tid * 16) =                   \
        make_uint4(w0, w1, w2, w3);                                          \
  }
#define CVT8(base)                          \
  {                                         \
    CVTPAIR(st[0], st[1], (base));          \
    CVTPAIR(st[2], st[3], (base) + 8192);   \
    CVTPAIR(st[4], st[5], (base) + 16384);  \
    CVTPAIR(st[6], st[7], (base) + 24576);  \
  }
#define PH_SYNC()                                    \
  __builtin_amdgcn_s_barrier();                      \
  asm volatile("s_waitcnt lgkmcnt(0)" ::: "memory"); \
  SB0;
#define LDA8(p, swz)                                                       \
  _Pragma("unroll") for (int i_ = 0; i_ < 8; ++i_) {                       \
    A8[i_] = *reinterpret_cast<const bf16x8*>((p) + i_ * 2048 + (swz));    \
  }
#define LDB2(p, fjb, swz)                                                  \
  {                                                                        \
    Bf[0] = *reinterpret_cast<const bf16x8*>((p) + (fjb) + (swz));         \
    Bf[1] = *reinterpret_cast<const bf16x8*>((p) + (fjb) + 2048 + (swz));  \
  }

  // ---- prologue: buf0 <- tile0 (A cvt + B stg); leave st = A(1) in flight.
  AISS8(0); SB0;
  CVT8(0);  // auto-wait vmcnt(0); writes buf0.A(tile0)
  SB0;
  STG(bS0, bS1, 0, 32768); STG(bS2, bS3, 0, 49152); SB0;
  AISS8(64); SB0;  // A(1) -> consumed at it0 ph2 CVT
  asm volatile("s_waitcnt vmcnt(8)" ::: "memory");  // drain B(0), keep st
  asm volatile("s_waitcnt lgkmcnt(0)" ::: "memory");
  BAR;
  SB0;

#define ITER(M)                                                           \
  {                                                                       \
    const int ktB1 = (2 * it + 1) * 64;                                   \
    const int ktB2 = (2 * it + 2) * 64;                                   \
    const int ktA2 = (2 * it + 2) * 64;                                   \
    const int ktA3 = (2 * it + 3) * 64;                                   \
    /* ph1: buf0 kk0 fj01; stage BOTH B(j+1) halves -> buf1.B */          \
    LDA8(p0A, swz0); LDB2(p0B, 0, swz0);                                  \
    STG(bS0, bS1, ktB1, 98304); STG(bS2, bS3, ktB1, 114688);              \
    PH_SYNC(); mfma16b<0>(acc, A8, Bf); BAR;                              \
    /* ph2: buf0 kk0 fj23; CVT st -> buf1.A(j+1); AISS st <- A(j+2) */    \
    LDB2(p0B, 4096, swz0);                                                \
    CVT8(65536);                                                          \
    SB0;                                                                  \
    if (M == 0) { AISS8(ktA2); SB0; }                                     \
    PH_SYNC(); mfma16b<2>(acc, A8, Bf); BAR;                              \
    /* ph3: buf0 kk1 fj01 */                                              \
    LDA8(p0A, swz1); LDB2(p0B, 0, swz1);                                  \
    PH_SYNC(); mfma16b<0>(acc, A8, Bf); BAR;                              \
    /* ph4: buf0 kk1 fj23; end: counted drain for B(j+1) */               \
    LDB2(p0B, 4096, swz1);                                                \
    PH_SYNC(); mfma16b<2>(acc, A8, Bf);                                   \
    SB0;                                                                  \
    if (M == 0) { asm volatile("s_waitcnt vmcnt(8)" ::: "memory"); }      \
    else        { asm volatile("s_waitcnt vmcnt(0)" ::: "memory"); }      \
    BAR; SB0;                                                             \
    /* ph5: buf1 kk0 fj01; stage BOTH B(j+2) halves -> buf0.B */          \
    LDA8(p1A, swz0); LDB2(p1B, 0, swz0);                                  \
    if (M == 0) { STG(bS0, bS1, ktB2, 32768); STG(bS2, bS3, ktB2, 49152); } \
    PH_SYNC(); mfma16b<0>(acc, A8, Bf); BAR;                              \
    /* ph6: buf1 kk0 fj23; CVT st -> buf0.A(j+2); AISS st <- A(j+3) */    \
    LDB2(p1B, 4096, swz0);                                                \
    if (M == 0) { CVT8(0); SB0; AISS8(ktA3); SB0; }                       \
    PH_SYNC(); mfma16b<2>(acc, A8, Bf); BAR;                              \
    /* ph7: buf1 kk1 fj01 */                                              \
    LDA8(p1A, swz1); LDB2(p1B, 0, swz1);                                  \
    PH_SYNC(); mfma16b<0>(acc, A8, Bf); BAR;                              \
    /* ph8: buf1 kk1 fj23; end: counted drain for B(j+2) */               \
    LDB2(p1B, 4096, swz1);                                                \
    PH_SYNC(); mfma16b<2>(acc, A8, Bf);                                   \
    if (M == 0) {                                                         \
      SB0;                                                                \
      asm volatile("s_waitcnt vmcnt(8)" ::: "memory");                    \
      BAR; SB0;                                                           \
    }                                                                     \
  }

#pragma unroll 1
  for (int it = 0; it < 7; ++it) ITER(0);
  { const int it = 7; ITER(1); }
#undef ITER
#undef STG
#undef AISS8
#undef CVTPAIR
#undef CVT8
#undef PH_SYNC
#undef LDA8
#undef LDB2
#undef SB0
#undef BAR

  // ---- epilogue: C/D layout col=lane&15, row=(lane>>4)*4+r ----
#pragma unroll
  for (int fi = 0; fi < 8; ++fi) {
#pragma unroll
    for (int fj = 0; fj < 4; ++fj) {
      int n = bn * 256 + wn * 64 + fj * 16 + lm;
      float bv = bias[n];
#pragma unroll
      for (int r = 0; r < 4; ++r) {
        size_t m = bm * 256 + wm * 128 + fi * 16 + ((lane >> 4) * 4) + r;
        Cg[m * 1024 + n] = f2bf(acc[fi][fj][r] + bv);
      }
    }
  }
}

// ---------------- 128x128 gload_lds GEMM (Q/O; verified) -------------------
template <typename TOUT>
__global__ __launch_bounds__(256) void gemm_lds(const ushort* __restrict__ Ag,
                                                const ushort* __restrict__ Wg,
                                                const float* __restrict__ bias,
                                                TOUT* __restrict__ Cg) {
  constexpr int K = 1024;
  __shared__ ushort lA[128 * 64];
  __shared__ ushort lB[128 * 64];
  const int tid = threadIdx.x;
  const int lane = tid & 63;
  const int wave = tid >> 6;
  const int wr = (wave >> 1) * 64;
  const int wc = (wave & 1) * 64;
  const int d = blockIdx.x;
  const int bn = (d >> 3) & 7;
  const size_t bm = (size_t)(d & 7) * (gridDim.x >> 6) + (d >> 6);

  const ushort* aB = Ag + bm * 128 * K;
  const ushort* bB = Wg + (size_t)bn * 128 * K;
  const int srow = wave * 32 + (lane >> 3);
  const int scol = ((lane & 7) ^ (lane >> 3)) * 8;
  char* lAc = (char*)lA;
  char* lBc = (char*)lB;

  f32x4 acc[4][4] = {};

  for (int kt = 0; kt < K; kt += 64) {
    __syncthreads();
#pragma unroll
    for (int c = 0; c < 4; ++c) {
      __builtin_amdgcn_global_load_lds(
          (gvp)(aB + (size_t)(srow + c * 8) * K + kt + scol),
          (lvp)(lAc + wave * 4096 + c * 1024), 16, 0, 0);
      __builtin_amdgcn_global_load_lds(
          (gvp)(bB + (size_t)(srow + c * 8) * K + kt + scol),
          (lvp)(lBc + wave * 4096 + c * 1024), 16, 0, 0);
    }
    __syncthreads();
#pragma unroll
    for (int kk = 0; kk < 2; ++kk) {
      bf16x8 af[4], bg[4];
#pragma unroll
      for (int fi = 0; fi < 4; ++fi) {
        int r = wr + fi * 16 + (lane & 15);
        int byte = (r * 128 + kk * 64 + ((lane >> 4) * 16)) ^ ((r & 7) << 4);
        af[fi] = *reinterpret_cast<const bf16x8*>(lAc + byte);
      }
#pragma unroll
      for (int fj = 0; fj < 4; ++fj) {
        int r = wc + fj * 16 + (lane & 15);
        int byte = (r * 128 + kk * 64 + ((lane >> 4) * 16)) ^ ((r & 7) << 4);
        bg[fj] = *reinterpret_cast<const bf16x8*>(lBc + byte);
      }
#pragma unroll
      for (int fi = 0; fi < 4; ++fi)
#pragma unroll
        for (int fj = 0; fj < 4; ++fj)
          acc[fi][fj] = __builtin_amdgcn_mfma_f32_16x16x32_bf16(af[fi], bg[fj],
                                                                acc[fi][fj], 0, 0, 0);
    }
  }
#pragma unroll
  for (int fi = 0; fi < 4; ++fi) {
#pragma unroll
    for (int fj = 0; fj < 4; ++fj) {
      int n = bn * 128 + wc + fj * 16 + (lane & 15);
      float bv = bias[n];
#pragma unroll
      for (int r = 0; r < 4; ++r) {
        size_t m = bm * 128 + wr + fi * 16 + ((lane >> 4) * 4) + r;
        float val = acc[fi][fj][r] + bv;
        if constexpr (sizeof(TOUT) == 2)
          reinterpret_cast<ushort*>(Cg)[m * 1024 + n] = f2bf(val);
        else
          reinterpret_cast<float*>(Cg)[m * 1024 + n] = val;
      }
    }
  }
}

// ------------- reg-staged GEMM (fp32 A): fallback path only ---------------
template <typename TIN, typename TOUT>
__global__ __launch_bounds__(256) void gemm_bias(const TIN* __restrict__ Ag,
                                                 const float* __restrict__ Wg,
                                                 const float* __restrict__ bias,
                                                 TOUT* __restrict__ Cg) {
  constexpr int K = 1024;
  __shared__ char lA[128 * 64 * 2];
  __shared__ char lB[128 * 64 * 2];
  const int tid = threadIdx.x;
  const int lane = tid & 63;
  const int wave = tid >> 6;
  const int wr = (wave >> 1) * 64;
  const int wc = (wave & 1) * 64;
  const int bn = blockIdx.x;
  const size_t bm = blockIdx.y;

  const TIN* aBase = Ag + bm * 128 * K;
  const float* bBase = Wg + (size_t)bn * 128 * K;

  f32x4 acc[4][4] = {};

  for (int kt = 0; kt < K; kt += 64) {
    __syncthreads();
    if constexpr (sizeof(TIN) == 4) {
#pragma unroll
      for (int i = 0; i < 8; ++i) {
        int f = tid + i * 256;
        int row = f >> 4, c4 = f & 15;
        const float4 v = *reinterpret_cast<const float4*>(
            reinterpret_cast<const float*>(aBase) + (size_t)row * K + kt + c4 * 4);
        ushort4 pk;
        pk.x = f2bf(v.x); pk.y = f2bf(v.y); pk.z = f2bf(v.z); pk.w = f2bf(v.w);
        int byte = (row * 128 + c4 * 8) ^ ((row & 7) << 4);
        *reinterpret_cast<ushort4*>(lA + byte) = pk;
      }
    } else {
#pragma unroll
      for (int i = 0; i < 4; ++i) {
        int f = tid + i * 256;
        int row = f >> 3, c8 = f & 7;
        int4 v = *reinterpret_cast<const int4*>(
            reinterpret_cast<const ushort*>(aBase) + (size_t)row * K + kt + c8 * 8);
        int byte = (row * 128 + c8 * 16) ^ ((row & 7) << 4);
        *reinterpret_cast<int4*>(lA + byte) = v;
      }
    }
#pragma unroll
    for (int i = 0; i < 8; ++i) {
      int f = tid + i * 256;
      int row = f >> 4, c4 = f & 15;
      const float4 v =
          *reinterpret_cast<const float4*>(bBase + (size_t)row * K + kt + c4 * 4);
      ushort4 pk;
      pk.x = f2bf(v.x); pk.y = f2bf(v.y); pk.z = f2bf(v.z); pk.w = f2bf(v.w);
      int byte = (row * 128 + c4 * 8) ^ ((row & 7) << 4);
      *reinterpret_cast<ushort4*>(lB + byte) = pk;
    }
    __syncthreads();
#pragma unroll
    for (int kk = 0; kk < 2; ++kk) {
      bf16x8 af[4], bg[4];
#pragma unroll
      for (int fi = 0; fi < 4; ++fi) {
        int r = wr + fi * 16 + (lane & 15);
        int byte = (r * 128 + kk * 64 + ((lane >> 4) * 16)) ^ ((r & 7) << 4);
        af[fi] = *reinterpret_cast<const bf16x8*>(lA + byte);
      }
#pragma unroll
      for (int fj = 0; fj < 4; ++fj) {
        int r = wc + fj * 16 + (lane & 15);
        int byte = (r * 128 + kk * 64 + ((lane >> 4) * 16)) ^ ((r & 7) << 4);
        bg[fj] = *reinterpret_cast<const bf16x8*>(lB + byte);
      }
#pragma unroll
      for (int fi = 0; fi < 4; ++fi)
#pragma unroll
        for (int fj = 0; fj < 4; ++fj)
          acc[fi][fj] =
              __builtin_amdgcn_mfma_f32_16x16x32_bf16(af[fi], bg[fj], acc[fi][fj], 0, 0, 0);
    }
  }
#pragma unroll
  for (int fi = 0; fi < 4; ++fi) {
#pragma unroll
    for (int fj = 0; fj < 4; ++fj) {
      int n = bn * 128 + wc + fj * 16 + (lane & 15);
      float bv = bias[n];
#pragma unroll
      for (int r = 0; r < 4; ++r) {
        size_t m = bm * 128 + wr + fi * 16 + ((lane >> 4) * 4) + r;
        float val = acc[fi][fj][r] + bv;
        if constexpr (sizeof(TOUT) == 2)
          reinterpret_cast<ushort*>(Cg)[m * 1024 + n] = f2bf(val);
        else
          reinterpret_cast<float*>(Cg)[m * 1024 + n] = val;
      }
    }
  }
}

// ---------------- attention: one block per (b,s'), head-axis softmax ------
__global__ __launch_bounds__(512) void attn_kernel(const ushort* __restrict__ Q,
                                                   const ushort* __restrict__ Kl,
                                                   const ushort* __restrict__ Vl,
                                                   ushort* __restrict__ Aout) {
  const int bs = blockIdx.x;
  const int b = bs >> 11, sp = bs & 2047;
  const int tid = threadIdx.x;
  const int wave = tid >> 6, lane = tid & 63;

  __shared__ ushort qrow[1024];
  __shared__ float sc[16][32];
  __shared__ float attnw[16][32];
  __shared__ float mx[32], rinv[32];

  reinterpret_cast<uint*>(qrow)[tid] =
      reinterpret_cast<const uint*>(Q + (size_t)bs * 1024)[tid];
  __syncthreads();

  const int wp = lane & 31, half = lane >> 5;
#pragma unroll
  for (int hh = 0; hh < 2; ++hh) {
    const int h = wave * 2 + hh;
    const int s_k = h * 128 + (sp >> 4);
    const int w_k = (sp & 15) * 2 + (wp >> 4);
    const ushort* kp =
        Kl + (((size_t)(b * 2048 + s_k) * 32) + w_k) * 1024 + (wp & 15) * 64 + half * 32;
    const ushort* qp = qrow + h * 64 + half * 32;
    float dot = 0.f;
#pragma unroll
    for (int j = 0; j < 32; j += 8) {
      int4 kv = *reinterpret_cast<const int4*>(kp + j);
      int4 qv = *reinterpret_cast<const int4*>(qp + j);
      const ushort* ka = reinterpret_cast<const ushort*>(&kv);
      const ushort* qa = reinterpret_cast<const ushort*>(&qv);
#pragma unroll
      for (int t = 0; t < 8; ++t) dot += bf2f(ka[t]) * bf2f(qa[t]);
    }
    dot += __shfl_xor(dot, 32);
    if (half == 0) sc[h][wp] = dot * 0.125f;
  }
  __syncthreads();
  if (tid < 32) {
    float m = sc[0][tid];
#pragma unroll
    for (int h = 1; h < 16; ++h) m = fmaxf(m, sc[h][tid]);
    float s = 0.f;
#pragma unroll
    for (int h = 0; h < 16; ++h) s += __expf(sc[h][tid] - m);
    mx[tid] = m;
    rinv[tid] = 1.f / s;
  }
  __syncthreads();
  if (lane < 32) {
#pragma unroll
    for (int hh = 0; hh < 2; ++hh) {
      const int h = wave * 2 + hh;
      attnw[h][lane] = __expf(sc[h][lane] - mx[lane]) * rinv[lane];
    }
  }
  __syncthreads();
#pragma unroll
  for (int hh = 0; hh < 2; ++hh) {
    const int h = wave * 2 + hh;
    const int s_k = h * 128 + (sp >> 4);
    const size_t vb = (((size_t)(b * 2048 + s_k) * 32) + (sp & 15) * 2) * 1024;
    float a = 0.f;
#pragma unroll
    for (int w2 = 0; w2 < 32; ++w2) {
      float wgt = attnw[h][w2];
      a += wgt * bf2f(Vl[vb + (size_t)(w2 >> 4) * 1024 + (w2 & 15) * 64 + lane]);
    }
    Aout[(((size_t)(b * 16 + h)) * 2048 + sp) * 64 + lane] = f2bf(a);
  }
}

extern "C" void kernel_launch(void* const* d_in, const int* in_sizes, int n_in,
                              void* d_out, int out_size, void* d_ws, size_t ws_size,
                              hipStream_t stream) {
  const float* q = (const float*)d_in[0];
  const float* k = (const float*)d_in[1];
  const float* v = (const float*)d_in[2];
  const float* Wq = (const float*)d_in[3];
  const float* bq = (const float*)d_in[4];
  const float* Wk = (const float*)d_in[5];
  const float* bk = (const float*)d_in[6];
  const float* Wv = (const float*)d_in[7];
  const float* bv = (const float*)d_in[8];
  const float* Wo = (const float*)d_in[9];
  const float* bo = (const float*)d_in[10];
  float* out = (float*)d_out;

  char* ws = (char*)d_ws;
  const size_t MB = 1u << 20;
  ushort* Qlin = (ushort*)ws;                    // 8 MiB
  ushort* Aws  = (ushort*)(ws + 8 * MB);         // 8 MiB
  ushort* wkbf = (ushort*)(ws + 16 * MB);        // 2 MiB
  ushort* wvbf = (ushort*)(ws + 18 * MB);        // 2 MiB
  ushort* wqbf = (ushort*)(ws + 20 * MB);        // 2 MiB
  ushort* wobf = (ushort*)(ws + 22 * MB);        // 2 MiB
  ushort* qbf  = (ushort*)(ws + 24 * MB);        // 8 MiB
  ushort* Klin = (ushort*)(ws + 32 * MB);        // 256 MiB
  ushort* Vlin = (ushort*)(ws + 288 * MB);       // 256 MiB
  const bool full = ws_size >= 800 * MB;

  if (full) {
    cast_kernel<<<dim3(512), 256, 0, stream>>>(Wq, wqbf, 1048576L);
    cast_kernel<<<dim3(512), 256, 0, stream>>>(Wk, wkbf, 1048576L);
    cast_kernel<<<dim3(512), 256, 0, stream>>>(Wv, wvbf, 1048576L);
    cast_kernel<<<dim3(512), 256, 0, stream>>>(Wo, wobf, 1048576L);
    cast_kernel<<<dim3(2048), 256, 0, stream>>>(q, qbf, 4194304L);
    gemm_lds<ushort><<<dim3(256), 256, 0, stream>>>(qbf, wqbf, bq, Qlin);
    gemm_big<<<dim3(2048), 512, 0, stream>>>(k, wkbf, bk, Klin);
    gemm_big<<<dim3(2048), 512, 0, stream>>>(v, wvbf, bv, Vlin);
    attn_kernel<<<dim3(4096), dim3(512), 0, stream>>>(Qlin, Klin, Vlin, Aws);
    gemm_lds<float><<<dim3(256), 256, 0, stream>>>(Aws, wobf, bo, out);
  } else {
    gemm_bias<float, ushort><<<dim3(8, 32), 256, 0, stream>>>(q, Wq, bq, Qlin);
    gemm_bias<float, ushort><<<dim3(8, 1024), 256, 0, stream>>>(k, Wk, bk, Klin);
    gemm_bias<float, ushort><<<dim3(8, 1024), 256, 0, stream>>>(v, Wv, bv, Vlin);
    attn_kernel<<<dim3(4096), dim3(512), 0, stream>>>(Qlin, Klin, Vlin, Aws);
    gemm_bias<ushort, float><<<dim3(8, 32), 256, 0, stream>>>(Aws, Wo, bo, out);
  }
}